// Round 12
// baseline (193.424 us; speedup 1.0000x reference)
//
#include <hip/hip_runtime.h>
#include <hip/hip_bf16.h>

#define N_NODES  100000
#define N_EDGES  1600000
#define N_GRAPHS 128
#define HID      64
#define NBUCK    256
#define NPB      391                 // nodes per bucket: ceil(100000/256)
#define CAP      8192                // per-bucket record capacity (mean 6250)
#define BLKA     1024
#define EPTA     4
#define EPBA     (BLKA * EPTA)       // 4096 edges per pass-A block
#define NBLKA    ((N_EDGES + EPBA - 1) / EPBA)   // 391

#define NTILES   (N_NODES / 16)      // 6250 (exact)
#define BLK2     512
#define WPB2     (BLK2 / 64)         // 8 waves per block
#define NBLK2    768                 // 3 blocks/CU exactly (48KB LDS -> 3 resident)
#define NWAVES2  (NBLK2 * WPB2)      // 6144
#define TCW      256                 // per-tile fixed-cost weight for balancing
#define IDXCAP   384                 // per-wave staged index capacity (mean 256, sd 16)
#define PCHUNK   16                  // pool chunks per graph

typedef short short8v __attribute__((ext_vector_type(8)));
typedef float float4v __attribute__((ext_vector_type(4)));

__device__ __forceinline__ float bl_lo(unsigned u) { return __uint_as_float(u << 16); }
__device__ __forceinline__ float bl_hi(unsigned u) { return __uint_as_float(u & 0xffff0000u); }
__device__ __forceinline__ unsigned short f2bf(float f) {
    unsigned u = __float_as_uint(f);
    u += 0x7fffu + ((u >> 16) & 1u);           // round-to-nearest-even
    return (unsigned short)(u >> 16);
}

// ---------------- Pass A: block-local LDS counting sort into 256 dst-range buckets ----------------
__global__ __launch_bounds__(1024) void bucketA(const int* __restrict__ src,
                                                const int* __restrict__ dst,
                                                int* __restrict__ bcnt,      // [NBUCK*16], line-padded
                                                int2* __restrict__ bbuf) {   // [NBUCK*CAP]
    __shared__ int cnt[NBUCK], scn[NBUCK], cur[NBUCK], gb[NBUCK];
    __shared__ int2 srt[EPBA];                    // 32 KB
    int tid = threadIdx.x;
    if (tid < NBUCK) cnt[tid] = 0;
    __syncthreads();

    int e0 = (blockIdx.x * BLKA + tid) * EPTA;
    int s[EPTA], d[EPTA], b[EPTA];
    int nv = 0;
    if (e0 + EPTA <= N_EDGES) {
        int4 s4 = *reinterpret_cast<const int4*>(src + e0);
        int4 d4 = *reinterpret_cast<const int4*>(dst + e0);
        s[0] = s4.x; s[1] = s4.y; s[2] = s4.z; s[3] = s4.w;
        d[0] = d4.x; d[1] = d4.y; d[2] = d4.z; d[3] = d4.w;
        nv = EPTA;
    } else {
        for (int e = e0; e < N_EDGES; ++e) { s[nv] = src[e]; d[nv] = dst[e]; ++nv; }
    }
    for (int k = 0; k < nv; ++k) {
        b[k] = (int)((unsigned)d[k] / (unsigned)NPB);
        atomicAdd(&cnt[b[k]], 1);
    }
    __syncthreads();

    if (tid < NBUCK) scn[tid] = cnt[tid];
    __syncthreads();
    for (int o = 1; o < NBUCK; o <<= 1) {
        int v = 0;
        if (tid < NBUCK && tid >= o) v = scn[tid - o];
        __syncthreads();
        if (tid < NBUCK && tid >= o) scn[tid] += v;
        __syncthreads();
    }
    if (tid < NBUCK) {
        int ex = scn[tid] - cnt[tid];
        cur[tid] = ex;
        gb[tid] = (cnt[tid] > 0) ? atomicAdd(&bcnt[tid * 16], cnt[tid]) : 0;
        scn[tid] = ex;
    }
    __syncthreads();

    for (int k = 0; k < nv; ++k) {
        int p = atomicAdd(&cur[b[k]], 1);
        srt[p] = make_int2(s[k], d[k]);
    }
    __syncthreads();

    int tot = scn[NBUCK - 1] + cnt[NBUCK - 1];
    for (int i = tid; i < tot; i += BLKA) {
        int2 r = srt[i];
        int bb = (int)((unsigned)r.y / (unsigned)NPB);
        bbuf[(size_t)bb * CAP + gb[bb] + (i - scn[bb])] = r;
    }
}

// ---------------- bucket base scan ----------------
__global__ __launch_bounds__(256) void scanBuck(const int* __restrict__ bcnt,
                                                int* __restrict__ bbase,
                                                int* __restrict__ off) {
    __shared__ int s[NBUCK];
    int t = threadIdx.x;
    int own = bcnt[t * 16];
    s[t] = own;
    __syncthreads();
    for (int o = 1; o < NBUCK; o <<= 1) {
        int v = (t >= o) ? s[t - o] : 0;
        __syncthreads();
        s[t] += v;
        __syncthreads();
    }
    bbase[t] = s[t] - own;
    if (t == NBUCK - 1) {
        bbase[NBUCK] = s[t];
        off[N_NODES] = s[t];
    }
}

// ---------------- Pass B: per-bucket CSR via LDS histogram + scan ----------------
__global__ __launch_bounds__(1024) void bucketB(const int2* __restrict__ bbuf,
                                                const int* __restrict__ bcnt,
                                                const int* __restrict__ bbase,
                                                int* __restrict__ off,
                                                int* __restrict__ esrc) {
    __shared__ int hist[NPB], scn[NPB], cur[NPB];
    int b = blockIdx.x, tid = threadIdx.x;
    int node0 = b * NPB;
    int ncnt = N_NODES - node0; if (ncnt > NPB) ncnt = NPB;
    if (tid < ncnt) hist[tid] = 0;
    __syncthreads();

    int cnt  = bcnt[b * 16];
    int base = bbase[b];
    const int2* buf = bbuf + (size_t)b * CAP;

    for (int i = tid; i < cnt; i += 1024)
        atomicAdd(&hist[buf[i].y - node0], 1);
    __syncthreads();

    if (tid < ncnt) scn[tid] = hist[tid];
    __syncthreads();
    for (int o = 1; o < NPB; o <<= 1) {
        int v = 0;
        if (tid < ncnt && tid >= o) v = scn[tid - o];
        __syncthreads();
        if (tid < ncnt && tid >= o) scn[tid] += v;
        __syncthreads();
    }
    if (tid < ncnt) {
        int ex = scn[tid] - hist[tid];
        off[node0 + tid] = base + ex;
        cur[tid] = ex;
    }
    __syncthreads();

    for (int i = tid; i < cnt; i += 1024) {
        int2 r = buf[i];
        int p = atomicAdd(&cur[r.y - node0], 1);
        esrc[base + p] = r.x;
    }
}

// ---------------- balanced tile partition: smallest t with off[16t]+TCW*t >= target ----------------
__device__ __forceinline__ int tile_bound(const int* __restrict__ off, long long target) {
    int lo = 0, hi = NTILES;
    while (lo < hi) {
        int mid = (lo + hi) >> 1;
        long long v = (long long)off[mid * 16] + (long long)TCW * mid;
        if (v < target) lo = mid + 1; else hi = mid;
    }
    return lo;
}

// ---------------- Layer 1: LDS-idx paired gather(x) + scalar layer-a + MFMA layer-b -> h1 (bf16) ----------------
__global__ __launch_bounds__(512, 8) void l1_mfma(const float* __restrict__ x,
                                                  const int* __restrict__ off,
                                                  const int* __restrict__ esrc,
                                                  const float* __restrict__ W1a,
                                                  const float* __restrict__ b1a,
                                                  const float* __restrict__ W1b,
                                                  const float* __restrict__ b1b,
                                                  unsigned short* __restrict__ h1b) {
    __shared__ float sWa[3 * 64];
    __shared__ float sba[64], sbb[64];
    __shared__ __align__(16) unsigned short sWbT[64 * 72];   // sWbT[n*72+k] = bf16(W1b[k][n])
    __shared__ __align__(16) unsigned short stA[WPB2][16][72];
    __shared__ int sIdx[WPB2][IDXCAP];

    int tid = threadIdx.x;
    for (int i = tid; i < 3 * 64; i += BLK2) sWa[i] = W1a[i];
    for (int i = tid; i < 64 * 64; i += BLK2) {
        int k = i >> 6, n = i & 63;
        sWbT[n * 72 + k] = f2bf(W1b[i]);
    }
    if (tid < 64) { sba[tid] = b1a[tid]; sbb[tid] = b1b[tid]; }
    __syncthreads();

    int w = tid >> 6;
    int l = tid & 63;
    int c  = l & 3;           // component 0..2 (lane c==3 contributes 0)
    int cc = (c < 3) ? c : 0;
    int ei = l >> 2;          // edge slot 0..15
    int m  = l & 15;          // A row / D col
    int kg = l >> 4;          // k-group / D row-group
    int wid = blockIdx.x * WPB2 + w;

    const long long TOT = (long long)N_EDGES + (long long)TCW * NTILES;
    int t0 = tile_bound(off, TOT * wid / NWAVES2);
    int t1 = tile_bound(off, TOT * (wid + 1) / NWAVES2);

    for (int t = t0; t < t1; ++t) {
        int nt0 = t * 16;
        int base = off[nt0];
        int span = off[nt0 + 16] - base;
        bool fits = (span <= IDXCAP);
        if (fits)
            for (int i = l; i < span; i += 64) sIdx[w][i] = esrc[base + i];
        __builtin_amdgcn_wave_barrier();

        for (int mm = 0; mm < 8; ++mm) {
            int n0 = nt0 + mm, n1 = nt0 + mm + 8;
            int sA = off[n0] - base, eA = off[n0 + 1] - base;
            int sB = off[n1] - base, eB = off[n1 + 1] - base;
            int emA = max(eA - 1, 0);
            int emB = max(eB - 1, 0);
            float a = 0.f, b = 0.f;
            if (fits) {
                for (int p0 = sA, p1 = sB; p0 < eA || p1 < eB; p0 += 16, p1 += 16) {
                    int pa = p0 + ei, pb = p1 + ei;
                    int ia = sIdx[w][min(pa, emA)];
                    int ib = sIdx[w][min(pb, emB)];
                    float va = x[ia * 3 + cc];
                    float vb = x[ib * 3 + cc];
                    if (c == 3 || pa >= eA) va = 0.f;
                    if (c == 3 || pb >= eB) vb = 0.f;
                    a += va; b += vb;
                }
            } else {
                for (int p0 = sA, p1 = sB; p0 < eA || p1 < eB; p0 += 16, p1 += 16) {
                    int pa = p0 + ei, pb = p1 + ei;
                    int ia = esrc[base + min(pa, emA)];
                    int ib = esrc[base + min(pb, emB)];
                    float va = x[ia * 3 + cc];
                    float vb = x[ib * 3 + cc];
                    if (c == 3 || pa >= eA) va = 0.f;
                    if (c == 3 || pb >= eB) vb = 0.f;
                    a += va; b += vb;
                }
            }
#pragma unroll
            for (int d = 4; d < 64; d <<= 1) {
                a += __shfl_xor(a, d);
                b += __shfl_xor(b, d);
            }
            float i00 = __shfl(a, 0) + x[n0 * 3 + 0];
            float i01 = __shfl(a, 1) + x[n0 * 3 + 1];
            float i02 = __shfl(a, 2) + x[n0 * 3 + 2];
            float i10 = __shfl(b, 0) + x[n1 * 3 + 0];
            float i11 = __shfl(b, 1) + x[n1 * 3 + 1];
            float i12 = __shfl(b, 2) + x[n1 * 3 + 2];
            float t0v = sba[l] + i00 * sWa[l] + i01 * sWa[64 + l] + i02 * sWa[128 + l];
            float t1v = sba[l] + i10 * sWa[l] + i11 * sWa[64 + l] + i12 * sWa[128 + l];
            stA[w][mm][l]     = f2bf(fmaxf(t0v, 0.0f));
            stA[w][mm + 8][l] = f2bf(fmaxf(t1v, 0.0f));
        }
        __builtin_amdgcn_wave_barrier();

        short8v A0 = *reinterpret_cast<const short8v*>(&stA[w][m][kg * 8]);
        short8v A1 = *reinterpret_cast<const short8v*>(&stA[w][m][32 + kg * 8]);
#pragma unroll
        for (int cq = 0; cq < 4; ++cq) {
            short8v B0 = *reinterpret_cast<const short8v*>(&sWbT[(16 * cq + m) * 72 + kg * 8]);
            short8v B1 = *reinterpret_cast<const short8v*>(&sWbT[(16 * cq + m) * 72 + 32 + kg * 8]);
            float bb = sbb[16 * cq + m];
            float4v acc = {bb, bb, bb, bb};
            acc = __builtin_amdgcn_mfma_f32_16x16x32_bf16(A0, B0, acc, 0, 0, 0);
            acc = __builtin_amdgcn_mfma_f32_16x16x32_bf16(A1, B1, acc, 0, 0, 0);
#pragma unroll
            for (int i = 0; i < 4; ++i)
                h1b[(size_t)(nt0 + kg * 4 + i) * 64 + 16 * cq + m] = f2bf(fmaxf(acc[i], 0.0f));
        }
        __builtin_amdgcn_wave_barrier();
    }
}

// ---------------- Layer 2: LDS-idx 4-deep bf16 gather + double MFMA MLP -> h2 (f32) ----------------
__global__ __launch_bounds__(512, 8) void l2_mfma(const unsigned* __restrict__ h1p,   // packed 2xbf16
                                                  const int* __restrict__ off,
                                                  const int* __restrict__ esrc,
                                                  const float* __restrict__ W2a,
                                                  const float* __restrict__ b2a,
                                                  const float* __restrict__ W2b,
                                                  const float* __restrict__ b2b,
                                                  float* __restrict__ h2) {
    __shared__ float sba[64], sbb[64];
    __shared__ __align__(16) unsigned short sWaT[64 * 72];   // sWaT[n*72+k] = bf16(W2a[k][n])
    __shared__ __align__(16) unsigned short sWbT[64 * 72];
    __shared__ __align__(16) unsigned short stA[WPB2][16][72];
    __shared__ int sIdx[WPB2][IDXCAP];

    int tid = threadIdx.x;
    for (int i = tid; i < 64 * 64; i += BLK2) {
        int k = i >> 6, n = i & 63;
        sWaT[n * 72 + k] = f2bf(W2a[i]);
        sWbT[n * 72 + k] = f2bf(W2b[i]);
    }
    if (tid < 64) { sba[tid] = b2a[tid]; sbb[tid] = b2b[tid]; }
    __syncthreads();

    int w = tid >> 6;
    int l = tid & 63;
    int g = l >> 4;          // edge slot 0..3
    int q = l & 15;          // 8B chunk of 128B row
    int m  = l & 15;
    int kg = l >> 4;
    int wid = blockIdx.x * WPB2 + w;

    const long long TOT = (long long)N_EDGES + (long long)TCW * NTILES;
    int t0 = tile_bound(off, TOT * wid / NWAVES2);
    int t1 = tile_bound(off, TOT * (wid + 1) / NWAVES2);

    for (int t = t0; t < t1; ++t) {
        int nt0 = t * 16;
        int base = off[nt0];
        int span = off[nt0 + 16] - base;
        bool fits = (span <= IDXCAP);
        if (fits)
            for (int i = l; i < span; i += 64) sIdx[w][i] = esrc[base + i];
        __builtin_amdgcn_wave_barrier();

        // ---- gather 16 nodes -> stA rows (bf16) ----
        for (int mm = 0; mm < 16; ++mm) {
            int n = nt0 + mm;
            int start = off[n] - base, end = off[n + 1] - base;
            int em = max(end - 1, 0);
            float a0 = 0.f, a1 = 0.f, a2 = 0.f, a3 = 0.f;
            if (g == 0) {      // self term once
                uint2 v = *reinterpret_cast<const uint2*>(h1p + (size_t)n * 32 + 2 * q);
                a0 += bl_lo(v.x); a1 += bl_hi(v.x); a2 += bl_lo(v.y); a3 += bl_hi(v.y);
            }
            if (fits) {
                for (int p = start; p < end; p += 16) {
                    int tA = p + g, tB = p + 4 + g, tC = p + 8 + g, tD = p + 12 + g;
                    int sa = sIdx[w][min(tA, em)];
                    int sb = sIdx[w][min(tB, em)];
                    int sc = sIdx[w][min(tC, em)];
                    int sd = sIdx[w][min(tD, em)];
                    uint2 vA = *reinterpret_cast<const uint2*>(h1p + (size_t)sa * 32 + 2 * q);
                    uint2 vB = *reinterpret_cast<const uint2*>(h1p + (size_t)sb * 32 + 2 * q);
                    uint2 vC = *reinterpret_cast<const uint2*>(h1p + (size_t)sc * 32 + 2 * q);
                    uint2 vD = *reinterpret_cast<const uint2*>(h1p + (size_t)sd * 32 + 2 * q);
                    unsigned mA = tA < end ? 0xffffffffu : 0u;
                    unsigned mB = tB < end ? 0xffffffffu : 0u;
                    unsigned mC = tC < end ? 0xffffffffu : 0u;
                    unsigned mD = tD < end ? 0xffffffffu : 0u;
                    a0 += (bl_lo(vA.x & mA) + bl_lo(vB.x & mB)) + (bl_lo(vC.x & mC) + bl_lo(vD.x & mD));
                    a1 += (bl_hi(vA.x & mA) + bl_hi(vB.x & mB)) + (bl_hi(vC.x & mC) + bl_hi(vD.x & mD));
                    a2 += (bl_lo(vA.y & mA) + bl_lo(vB.y & mB)) + (bl_lo(vC.y & mC) + bl_lo(vD.y & mD));
                    a3 += (bl_hi(vA.y & mA) + bl_hi(vB.y & mB)) + (bl_hi(vC.y & mC) + bl_hi(vD.y & mD));
                }
            } else {
                for (int p = start; p < end; p += 16) {
                    int tA = p + g, tB = p + 4 + g, tC = p + 8 + g, tD = p + 12 + g;
                    int sa = esrc[base + min(tA, em)];
                    int sb = esrc[base + min(tB, em)];
                    int sc = esrc[base + min(tC, em)];
                    int sd = esrc[base + min(tD, em)];
                    uint2 vA = *reinterpret_cast<const uint2*>(h1p + (size_t)sa * 32 + 2 * q);
                    uint2 vB = *reinterpret_cast<const uint2*>(h1p + (size_t)sb * 32 + 2 * q);
                    uint2 vC = *reinterpret_cast<const uint2*>(h1p + (size_t)sc * 32 + 2 * q);
                    uint2 vD = *reinterpret_cast<const uint2*>(h1p + (size_t)sd * 32 + 2 * q);
                    unsigned mA = tA < end ? 0xffffffffu : 0u;
                    unsigned mB = tB < end ? 0xffffffffu : 0u;
                    unsigned mC = tC < end ? 0xffffffffu : 0u;
                    unsigned mD = tD < end ? 0xffffffffu : 0u;
                    a0 += (bl_lo(vA.x & mA) + bl_lo(vB.x & mB)) + (bl_lo(vC.x & mC) + bl_lo(vD.x & mD));
                    a1 += (bl_hi(vA.x & mA) + bl_hi(vB.x & mB)) + (bl_hi(vC.x & mC) + bl_hi(vD.x & mD));
                    a2 += (bl_lo(vA.y & mA) + bl_lo(vB.y & mB)) + (bl_lo(vC.y & mC) + bl_lo(vD.y & mD));
                    a3 += (bl_hi(vA.y & mA) + bl_hi(vB.y & mB)) + (bl_hi(vC.y & mC) + bl_hi(vD.y & mD));
                }
            }
            a0 += __shfl_xor(a0, 16); a0 += __shfl_xor(a0, 32);
            a1 += __shfl_xor(a1, 16); a1 += __shfl_xor(a1, 32);
            a2 += __shfl_xor(a2, 16); a2 += __shfl_xor(a2, 32);
            a3 += __shfl_xor(a3, 16); a3 += __shfl_xor(a3, 32);
            if (g == 0) {
                uint2 pk;
                pk.x = ((unsigned)f2bf(a1) << 16) | (unsigned)f2bf(a0);
                pk.y = ((unsigned)f2bf(a3) << 16) | (unsigned)f2bf(a2);
                *reinterpret_cast<uint2*>(&stA[w][mm][4 * q]) = pk;
            }
        }
        __builtin_amdgcn_wave_barrier();

        // ---- matmul1: relu(agg @ W2a + b2a), restage as bf16 ----
        short8v A0 = *reinterpret_cast<const short8v*>(&stA[w][m][kg * 8]);
        short8v A1 = *reinterpret_cast<const short8v*>(&stA[w][m][32 + kg * 8]);
#pragma unroll
        for (int cq = 0; cq < 4; ++cq) {
            short8v B0 = *reinterpret_cast<const short8v*>(&sWaT[(16 * cq + m) * 72 + kg * 8]);
            short8v B1 = *reinterpret_cast<const short8v*>(&sWaT[(16 * cq + m) * 72 + 32 + kg * 8]);
            float bb = sba[16 * cq + m];
            float4v acc = {bb, bb, bb, bb};
            acc = __builtin_amdgcn_mfma_f32_16x16x32_bf16(A0, B0, acc, 0, 0, 0);
            acc = __builtin_amdgcn_mfma_f32_16x16x32_bf16(A1, B1, acc, 0, 0, 0);
#pragma unroll
            for (int i = 0; i < 4; ++i)
                stA[w][kg * 4 + i][16 * cq + m] = f2bf(fmaxf(acc[i], 0.0f));
        }
        __builtin_amdgcn_wave_barrier();

        // ---- matmul2: relu(h @ W2b + b2b) -> h2 ----
        short8v C0 = *reinterpret_cast<const short8v*>(&stA[w][m][kg * 8]);
        short8v C1 = *reinterpret_cast<const short8v*>(&stA[w][m][32 + kg * 8]);
#pragma unroll
        for (int cq = 0; cq < 4; ++cq) {
            short8v B0 = *reinterpret_cast<const short8v*>(&sWbT[(16 * cq + m) * 72 + kg * 8]);
            short8v B1 = *reinterpret_cast<const short8v*>(&sWbT[(16 * cq + m) * 72 + 32 + kg * 8]);
            float bb = sbb[16 * cq + m];
            float4v acc = {bb, bb, bb, bb};
            acc = __builtin_amdgcn_mfma_f32_16x16x32_bf16(C0, B0, acc, 0, 0, 0);
            acc = __builtin_amdgcn_mfma_f32_16x16x32_bf16(C1, B1, acc, 0, 0, 0);
#pragma unroll
            for (int i = 0; i < 4; ++i)
                h2[(size_t)(nt0 + kg * 4 + i) * 64 + 16 * cq + m] = fmaxf(acc[i], 0.0f);
        }
        __builtin_amdgcn_wave_barrier();
    }
}

// ---------------- Pool stage A: per-(graph, chunk) partial sums ----------------
__global__ __launch_bounds__(256) void poolA(const float* __restrict__ h2,
                                             const int* __restrict__ batch,
                                             float* __restrict__ partial) {  // [PCHUNK][N_GRAPHS][64]
    int g = blockIdx.x & (N_GRAPHS - 1);
    int c = blockIdx.x >> 7;

    int lo = 0, hi = N_NODES;
    while (lo < hi) { int mid = (lo + hi) >> 1; if (batch[mid] < g) lo = mid + 1; else hi = mid; }
    int start = lo;
    lo = start; hi = N_NODES;
    while (lo < hi) { int mid = (lo + hi) >> 1; if (batch[mid] < g + 1) lo = mid + 1; else hi = mid; }
    int end = lo;

    int len = end - start;
    int cs = start + (int)((long long)len * c / PCHUNK);
    int ce = start + (int)((long long)len * (c + 1) / PCHUNK);

    int j = threadIdx.x & 63;
    int r = threadIdx.x >> 6;
    float local = 0.0f;
    for (int n = cs + r; n < ce; n += 4)
        local += h2[(size_t)n * 64 + j];

    __shared__ float red[4][64];
    red[r][j] = local;
    __syncthreads();
    if (r == 0)
        partial[((size_t)c * N_GRAPHS + g) * 64 + j] = red[0][j] + red[1][j] + red[2][j] + red[3][j];
}

// ---------------- Pool stage B: reduce chunks, divide by count ----------------
__global__ __launch_bounds__(64) void poolB(const float* __restrict__ partial,
                                            const int* __restrict__ batch,
                                            float* __restrict__ out) {
    int g = blockIdx.x;
    int j = threadIdx.x;

    int lo = 0, hi = N_NODES;
    while (lo < hi) { int mid = (lo + hi) >> 1; if (batch[mid] < g) lo = mid + 1; else hi = mid; }
    int start = lo;
    lo = start; hi = N_NODES;
    while (lo < hi) { int mid = (lo + hi) >> 1; if (batch[mid] < g + 1) lo = mid + 1; else hi = mid; }
    int end = lo;

    float s = 0.0f;
#pragma unroll
    for (int c = 0; c < PCHUNK; ++c)
        s += partial[((size_t)c * N_GRAPHS + g) * 64 + j];
    float cnt = (float)((end - start) > 1 ? (end - start) : 1);
    out[g * 64 + j] = s / cnt;
}

extern "C" void kernel_launch(void* const* d_in, const int* in_sizes, int n_in,
                              void* d_out, int out_size, void* d_ws, size_t ws_size,
                              hipStream_t stream) {
    const float* x    = (const float*)d_in[0];
    const int*   ei   = (const int*)d_in[1];
    const int*   bat  = (const int*)d_in[2];
    const float* W1a  = (const float*)d_in[3];
    const float* b1a  = (const float*)d_in[4];
    const float* W1b  = (const float*)d_in[5];
    const float* b1b  = (const float*)d_in[6];
    const float* W2a  = (const float*)d_in[7];
    const float* b2a  = (const float*)d_in[8];
    const float* W2b  = (const float*)d_in[9];
    const float* b2b  = (const float*)d_in[10];
    float* out = (float*)d_out;

    const int* src = ei;
    const int* dst = ei + N_EDGES;

    char* ws = (char*)d_ws;
    auto alignup = [](size_t v) { return (v + 255) & ~(size_t)255; };
    int*   bcnt  = (int*)ws;                       ws += alignup((size_t)NBUCK * 16 * 4);
    int*   bbase = (int*)ws;                       ws += alignup((size_t)(NBUCK + 1) * 4);
    int*   off   = (int*)ws;                       ws += alignup((size_t)(N_NODES + 1) * 4);
    int*   esrc  = (int*)ws;                       ws += alignup((size_t)N_EDGES * 4);
    unsigned short* h1b = (unsigned short*)ws;     ws += alignup((size_t)N_NODES * HID * 2);
    float* partial = (float*)ws;                   ws += alignup((size_t)PCHUNK * N_GRAPHS * 64 * 4);
    // bbuf and h2 share a slab: bbuf dead before l2_mfma writes h2
    int2*  bbuf  = (int2*)ws;
    float* h2    = (float*)ws;

    hipMemsetAsync(bcnt, 0, (size_t)NBUCK * 16 * 4, stream);

    bucketA<<<NBLKA, BLKA, 0, stream>>>(src, dst, bcnt, bbuf);
    scanBuck<<<1, 256, 0, stream>>>(bcnt, bbase, off);
    bucketB<<<NBUCK, 1024, 0, stream>>>(bbuf, bcnt, bbase, off, esrc);

    l1_mfma<<<NBLK2, BLK2, 0, stream>>>(x, off, esrc, W1a, b1a, W1b, b1b, h1b);
    l2_mfma<<<NBLK2, BLK2, 0, stream>>>((const unsigned*)h1b, off, esrc, W2a, b2a, W2b, b2b, h2);

    poolA<<<N_GRAPHS * PCHUNK, 256, 0, stream>>>(h2, bat, partial);
    poolB<<<N_GRAPHS, 64, 0, stream>>>(partial, bat, out);
}

// Round 13
// 150.611 us; speedup vs baseline: 1.2843x; 1.2843x over previous
//
#include <hip/hip_runtime.h>
#include <hip/hip_bf16.h>

#define N_NODES  100000
#define N_EDGES  1600000
#define N_GRAPHS 128
#define HID      64
#define NBUCK    256
#define NPB      391                 // nodes per bucket: ceil(100000/256)
#define CAP      8192                // per-bucket record capacity (mean 6250)
#define BLKA     1024
#define EPTA     4
#define EPBA     (BLKA * EPTA)       // 4096 edges per pass-A block
#define NBLKA    ((N_EDGES + EPBA - 1) / EPBA)   // 391

#define NTILES   (N_NODES / 16)      // 6250 (exact)
#define BLK2     512
#define WPB2     (BLK2 / 64)         // 8 waves per block
#define NBLK2    1024                // 8192 waves
#define NWAVES2  (NBLK2 * WPB2)      // 8192
#define TCW      256                 // per-tile fixed-cost weight for balancing
#define PCHUNK   16                  // pool chunks per graph

typedef short short8v __attribute__((ext_vector_type(8)));
typedef float float4v __attribute__((ext_vector_type(4)));

__device__ __forceinline__ float bl_lo(unsigned u) { return __uint_as_float(u << 16); }
__device__ __forceinline__ float bl_hi(unsigned u) { return __uint_as_float(u & 0xffff0000u); }
__device__ __forceinline__ unsigned short f2bf(float f) {
    unsigned u = __float_as_uint(f);
    u += 0x7fffu + ((u >> 16) & 1u);           // round-to-nearest-even
    return (unsigned short)(u >> 16);
}

// ---------------- Pass A: LDS counting sort into 256 dst-range buckets; PACKED records ----------------
// rec = src | (loc << 17), loc = dst - bucket*NPB  (src < 2^17, loc < 391 < 2^9)
__global__ __launch_bounds__(1024) void bucketA(const int* __restrict__ src,
                                                const int* __restrict__ dst,
                                                int* __restrict__ bcnt,      // [NBUCK*16], line-padded
                                                int* __restrict__ bbuf) {    // [NBUCK*CAP] packed
    __shared__ int cnt[NBUCK], scn[NBUCK], cur[NBUCK], gb[NBUCK];
    __shared__ int srt[EPBA];                     // 16 KB
    int tid = threadIdx.x;
    if (tid < NBUCK) cnt[tid] = 0;
    __syncthreads();

    int e0 = (blockIdx.x * BLKA + tid) * EPTA;
    int s[EPTA], d[EPTA], b[EPTA];
    int nv = 0;
    if (e0 + EPTA <= N_EDGES) {
        int4 s4 = *reinterpret_cast<const int4*>(src + e0);
        int4 d4 = *reinterpret_cast<const int4*>(dst + e0);
        s[0] = s4.x; s[1] = s4.y; s[2] = s4.z; s[3] = s4.w;
        d[0] = d4.x; d[1] = d4.y; d[2] = d4.z; d[3] = d4.w;
        nv = EPTA;
    } else {
        for (int e = e0; e < N_EDGES; ++e) { s[nv] = src[e]; d[nv] = dst[e]; ++nv; }
    }
    for (int k = 0; k < nv; ++k) {
        b[k] = (int)((unsigned)d[k] / (unsigned)NPB);
        atomicAdd(&cnt[b[k]], 1);
    }
    __syncthreads();

    if (tid < NBUCK) scn[tid] = cnt[tid];
    __syncthreads();
    for (int o = 1; o < NBUCK; o <<= 1) {
        int v = 0;
        if (tid < NBUCK && tid >= o) v = scn[tid - o];
        __syncthreads();
        if (tid < NBUCK && tid >= o) scn[tid] += v;
        __syncthreads();
    }
    if (tid < NBUCK) {
        int ex = scn[tid] - cnt[tid];
        cur[tid] = ex;
        gb[tid] = (cnt[tid] > 0) ? atomicAdd(&bcnt[tid * 16], cnt[tid]) : 0;
        scn[tid] = ex;
    }
    __syncthreads();

    for (int k = 0; k < nv; ++k) {
        int p = atomicAdd(&cur[b[k]], 1);
        int loc = d[k] - b[k] * NPB;
        srt[p] = s[k] | (loc << 17);
    }
    __syncthreads();

    // per-bucket LDS ranges -> bucket id per element via binary search is avoidable:
    // iterate buckets per element by recomputing from srt? Instead store bucket in high bits?
    // loc<<17 occupies bits 17..25; we still need the bucket id for the copy-out.
    // Recover it: element i belongs to bucket bb iff scn[bb] <= i < scn[bb]+cnt[bb].
    // Use a second LDS array mapping positions -> bucket via the scan (binary search over scn).
    int tot = scn[NBUCK - 1] + cnt[NBUCK - 1];
    for (int i = tid; i < tot; i += BLKA) {
        int lo = 0, hi = NBUCK - 1;
        while (lo < hi) {                          // largest bb with scn[bb] <= i
            int mid = (lo + hi + 1) >> 1;
            if (scn[mid] <= i) lo = mid; else hi = mid - 1;
        }
        int bb = lo;
        bbuf[(size_t)bb * CAP + gb[bb] + (i - scn[bb])] = srt[i];
    }
}

// ---------------- bucket base scan ----------------
__global__ __launch_bounds__(256) void scanBuck(const int* __restrict__ bcnt,
                                                int* __restrict__ bbase,
                                                int* __restrict__ off) {
    __shared__ int s[NBUCK];
    int t = threadIdx.x;
    int own = bcnt[t * 16];
    s[t] = own;
    __syncthreads();
    for (int o = 1; o < NBUCK; o <<= 1) {
        int v = (t >= o) ? s[t - o] : 0;
        __syncthreads();
        s[t] += v;
        __syncthreads();
    }
    bbase[t] = s[t] - own;
    if (t == NBUCK - 1) {
        bbase[NBUCK] = s[t];
        off[N_NODES] = s[t];
    }
}

// ---------------- Pass B: per-bucket CSR via LDS histogram + scan (packed records) ----------------
__global__ __launch_bounds__(1024) void bucketB(const int* __restrict__ bbuf,
                                                const int* __restrict__ bcnt,
                                                const int* __restrict__ bbase,
                                                int* __restrict__ off,
                                                int* __restrict__ esrc) {
    __shared__ int hist[NPB], scn[NPB], cur[NPB];
    int b = blockIdx.x, tid = threadIdx.x;
    int node0 = b * NPB;
    int ncnt = N_NODES - node0; if (ncnt > NPB) ncnt = NPB;
    if (tid < NPB) hist[tid] = 0;
    __syncthreads();

    int cnt  = bcnt[b * 16];
    int base = bbase[b];
    const int* buf = bbuf + (size_t)b * CAP;

    for (int i = tid; i < cnt; i += 1024)
        atomicAdd(&hist[((unsigned)buf[i]) >> 17], 1);
    __syncthreads();

    if (tid < NPB) scn[tid] = hist[tid];
    __syncthreads();
    for (int o = 1; o < NPB; o <<= 1) {
        int v = 0;
        if (tid < NPB && tid >= o) v = scn[tid - o];
        __syncthreads();
        if (tid < NPB && tid >= o) scn[tid] += v;
        __syncthreads();
    }
    if (tid < ncnt) {
        int ex = scn[tid] - hist[tid];
        off[node0 + tid] = base + ex;
        cur[tid] = ex;
    }
    __syncthreads();

    for (int i = tid; i < cnt; i += 1024) {
        int rec = buf[i];
        int loc = ((unsigned)rec) >> 17;
        int p = atomicAdd(&cur[loc], 1);
        esrc[base + p] = rec & 0x1FFFF;
    }
}

// ---------------- balanced tile partition: smallest t with off[16t]+TCW*t >= target ----------------
__device__ __forceinline__ int tile_bound(const int* __restrict__ off, long long target) {
    int lo = 0, hi = NTILES;
    while (lo < hi) {
        int mid = (lo + hi) >> 1;
        long long v = (long long)off[mid * 16] + (long long)TCW * mid;
        if (v < target) lo = mid + 1; else hi = mid;
    }
    return lo;
}

// ---------------- Layer 1: paired-node gather(x) + scalar layer-a + MFMA layer-b -> h1 (bf16) ----------------
__global__ __launch_bounds__(512, 8) void l1_mfma(const float* __restrict__ x,
                                                  const int* __restrict__ off,
                                                  const int* __restrict__ esrc,
                                                  const float* __restrict__ W1a,
                                                  const float* __restrict__ b1a,
                                                  const float* __restrict__ W1b,
                                                  const float* __restrict__ b1b,
                                                  unsigned short* __restrict__ h1b) {
    __shared__ float sWa[3 * 64];
    __shared__ float sba[64], sbb[64];
    __shared__ __align__(16) unsigned short sWbT[64 * 72];   // sWbT[n*72+k] = bf16(W1b[k][n])
    __shared__ __align__(16) unsigned short stA[WPB2][16][72];

    int tid = threadIdx.x;
    for (int i = tid; i < 3 * 64; i += BLK2) sWa[i] = W1a[i];
    for (int i = tid; i < 64 * 64; i += BLK2) {
        int k = i >> 6, n = i & 63;
        sWbT[n * 72 + k] = f2bf(W1b[i]);
    }
    if (tid < 64) { sba[tid] = b1a[tid]; sbb[tid] = b1b[tid]; }
    __syncthreads();

    int w = tid >> 6;
    int l = tid & 63;
    int c  = l & 3;           // component 0..2 (lane c==3 contributes 0)
    int cc = (c < 3) ? c : 0;
    int ei = l >> 2;          // edge slot 0..15
    int m  = l & 15;          // A row / D col
    int kg = l >> 4;          // k-group / D row-group
    int wid = blockIdx.x * WPB2 + w;

    const long long TOT = (long long)N_EDGES + (long long)TCW * NTILES;
    int t0 = tile_bound(off, TOT * wid / NWAVES2);
    int t1 = tile_bound(off, TOT * (wid + 1) / NWAVES2);

    for (int t = t0; t < t1; ++t) {
        int nt0 = t * 16;
        for (int mm = 0; mm < 8; ++mm) {
            int n0 = nt0 + mm, n1 = nt0 + mm + 8;
            int sA = off[n0], eA = off[n0 + 1];
            int sB = off[n1], eB = off[n1 + 1];
            int emA = max(eA - 1, 0);
            int emB = max(eB - 1, 0);
            float a = 0.f, b = 0.f;
            for (int e0 = sA, e1 = sB; e0 < eA || e1 < eB; e0 += 16, e1 += 16) {
                int ea_ = e0 + ei;
                int eb_ = e1 + ei;
                int ia = min(ea_, emA);
                int ib = min(eb_, emB);
                int sa = esrc[ia];
                int sb = esrc[ib];
                float va = x[sa * 3 + cc];
                float vb = x[sb * 3 + cc];
                if (c == 3 || ea_ >= eA) va = 0.f;
                if (c == 3 || eb_ >= eB) vb = 0.f;
                a += va; b += vb;
            }
#pragma unroll
            for (int d = 4; d < 64; d <<= 1) {
                a += __shfl_xor(a, d);
                b += __shfl_xor(b, d);
            }
            float i00 = __shfl(a, 0) + x[n0 * 3 + 0];
            float i01 = __shfl(a, 1) + x[n0 * 3 + 1];
            float i02 = __shfl(a, 2) + x[n0 * 3 + 2];
            float i10 = __shfl(b, 0) + x[n1 * 3 + 0];
            float i11 = __shfl(b, 1) + x[n1 * 3 + 1];
            float i12 = __shfl(b, 2) + x[n1 * 3 + 2];
            float t0v = sba[l] + i00 * sWa[l] + i01 * sWa[64 + l] + i02 * sWa[128 + l];
            float t1v = sba[l] + i10 * sWa[l] + i11 * sWa[64 + l] + i12 * sWa[128 + l];
            stA[w][mm][l]     = f2bf(fmaxf(t0v, 0.0f));
            stA[w][mm + 8][l] = f2bf(fmaxf(t1v, 0.0f));
        }
        __builtin_amdgcn_wave_barrier();

        short8v A0 = *reinterpret_cast<const short8v*>(&stA[w][m][kg * 8]);
        short8v A1 = *reinterpret_cast<const short8v*>(&stA[w][m][32 + kg * 8]);
#pragma unroll
        for (int cq = 0; cq < 4; ++cq) {
            short8v B0 = *reinterpret_cast<const short8v*>(&sWbT[(16 * cq + m) * 72 + kg * 8]);
            short8v B1 = *reinterpret_cast<const short8v*>(&sWbT[(16 * cq + m) * 72 + 32 + kg * 8]);
            float bb = sbb[16 * cq + m];
            float4v acc = {bb, bb, bb, bb};
            acc = __builtin_amdgcn_mfma_f32_16x16x32_bf16(A0, B0, acc, 0, 0, 0);
            acc = __builtin_amdgcn_mfma_f32_16x16x32_bf16(A1, B1, acc, 0, 0, 0);
#pragma unroll
            for (int i = 0; i < 4; ++i)
                h1b[(size_t)(nt0 + kg * 4 + i) * 64 + 16 * cq + m] = f2bf(fmaxf(acc[i], 0.0f));
        }
        __builtin_amdgcn_wave_barrier();
    }
}

// ---------------- Layer 2: 4-slot bf16 gather + double MFMA MLP -> h2 (f32)  [R10 structure] ----------------
__global__ __launch_bounds__(512, 8) void l2_mfma(const unsigned* __restrict__ h1p,   // packed 2xbf16
                                                  const int* __restrict__ off,
                                                  const int* __restrict__ esrc,
                                                  const float* __restrict__ W2a,
                                                  const float* __restrict__ b2a,
                                                  const float* __restrict__ W2b,
                                                  const float* __restrict__ b2b,
                                                  float* __restrict__ h2) {
    __shared__ float sba[64], sbb[64];
    __shared__ __align__(16) unsigned short sWaT[64 * 72];   // sWaT[n*72+k] = bf16(W2a[k][n])
    __shared__ __align__(16) unsigned short sWbT[64 * 72];
    __shared__ __align__(16) unsigned short stA[WPB2][16][72];

    int tid = threadIdx.x;
    for (int i = tid; i < 64 * 64; i += BLK2) {
        int k = i >> 6, n = i & 63;
        sWaT[n * 72 + k] = f2bf(W2a[i]);
        sWbT[n * 72 + k] = f2bf(W2b[i]);
    }
    if (tid < 64) { sba[tid] = b2a[tid]; sbb[tid] = b2b[tid]; }
    __syncthreads();

    int w = tid >> 6;
    int l = tid & 63;
    int g = l >> 4;          // edge slot 0..3
    int q = l & 15;          // 8B chunk of 128B row
    int m  = l & 15;
    int kg = l >> 4;
    int wid = blockIdx.x * WPB2 + w;

    const long long TOT = (long long)N_EDGES + (long long)TCW * NTILES;
    int t0 = tile_bound(off, TOT * wid / NWAVES2);
    int t1 = tile_bound(off, TOT * (wid + 1) / NWAVES2);

    for (int t = t0; t < t1; ++t) {
        int nt0 = t * 16;
        // ---- gather 16 nodes -> stA rows (bf16) ----
        for (int mm = 0; mm < 16; ++mm) {
            int n = nt0 + mm;
            int start = off[n], end = off[n + 1];
            int em = max(end - 1, 0);
            float a0 = 0.f, a1 = 0.f, a2 = 0.f, a3 = 0.f;
            if (g == 0) {      // self term once
                uint2 v = *reinterpret_cast<const uint2*>(h1p + (size_t)n * 32 + 2 * q);
                a0 += bl_lo(v.x); a1 += bl_hi(v.x); a2 += bl_lo(v.y); a3 += bl_hi(v.y);
            }
            for (int e = start; e < end; e += 16) {
                int tA = e + g, tB = e + 4 + g, tC = e + 8 + g, tD = e + 12 + g;
                int iA = min(tA, em);
                int iB = min(tB, em);
                int iC = min(tC, em);
                int iD = min(tD, em);
                int sa = esrc[iA], sb = esrc[iB], sc = esrc[iC], sd = esrc[iD];
                uint2 vA = *reinterpret_cast<const uint2*>(h1p + (size_t)sa * 32 + 2 * q);
                uint2 vB = *reinterpret_cast<const uint2*>(h1p + (size_t)sb * 32 + 2 * q);
                uint2 vC = *reinterpret_cast<const uint2*>(h1p + (size_t)sc * 32 + 2 * q);
                uint2 vD = *reinterpret_cast<const uint2*>(h1p + (size_t)sd * 32 + 2 * q);
                unsigned mA = tA < end ? 0xffffffffu : 0u;
                unsigned mB = tB < end ? 0xffffffffu : 0u;
                unsigned mC = tC < end ? 0xffffffffu : 0u;
                unsigned mD = tD < end ? 0xffffffffu : 0u;
                a0 += (bl_lo(vA.x & mA) + bl_lo(vB.x & mB)) + (bl_lo(vC.x & mC) + bl_lo(vD.x & mD));
                a1 += (bl_hi(vA.x & mA) + bl_hi(vB.x & mB)) + (bl_hi(vC.x & mC) + bl_hi(vD.x & mD));
                a2 += (bl_lo(vA.y & mA) + bl_lo(vB.y & mB)) + (bl_lo(vC.y & mC) + bl_lo(vD.y & mD));
                a3 += (bl_hi(vA.y & mA) + bl_hi(vB.y & mB)) + (bl_hi(vC.y & mC) + bl_hi(vD.y & mD));
            }
            a0 += __shfl_xor(a0, 16); a0 += __shfl_xor(a0, 32);
            a1 += __shfl_xor(a1, 16); a1 += __shfl_xor(a1, 32);
            a2 += __shfl_xor(a2, 16); a2 += __shfl_xor(a2, 32);
            a3 += __shfl_xor(a3, 16); a3 += __shfl_xor(a3, 32);
            if (g == 0) {
                uint2 pk;
                pk.x = ((unsigned)f2bf(a1) << 16) | (unsigned)f2bf(a0);
                pk.y = ((unsigned)f2bf(a3) << 16) | (unsigned)f2bf(a2);
                *reinterpret_cast<uint2*>(&stA[w][mm][4 * q]) = pk;
            }
        }
        __builtin_amdgcn_wave_barrier();

        // ---- matmul1: relu(agg @ W2a + b2a), restage as bf16 ----
        short8v A0 = *reinterpret_cast<const short8v*>(&stA[w][m][kg * 8]);
        short8v A1 = *reinterpret_cast<const short8v*>(&stA[w][m][32 + kg * 8]);
#pragma unroll
        for (int cq = 0; cq < 4; ++cq) {
            short8v B0 = *reinterpret_cast<const short8v*>(&sWaT[(16 * cq + m) * 72 + kg * 8]);
            short8v B1 = *reinterpret_cast<const short8v*>(&sWaT[(16 * cq + m) * 72 + 32 + kg * 8]);
            float bb = sba[16 * cq + m];
            float4v acc = {bb, bb, bb, bb};
            acc = __builtin_amdgcn_mfma_f32_16x16x32_bf16(A0, B0, acc, 0, 0, 0);
            acc = __builtin_amdgcn_mfma_f32_16x16x32_bf16(A1, B1, acc, 0, 0, 0);
#pragma unroll
            for (int i = 0; i < 4; ++i)
                stA[w][kg * 4 + i][16 * cq + m] = f2bf(fmaxf(acc[i], 0.0f));
        }
        __builtin_amdgcn_wave_barrier();

        // ---- matmul2: relu(h @ W2b + b2b) -> h2 ----
        short8v C0 = *reinterpret_cast<const short8v*>(&stA[w][m][kg * 8]);
        short8v C1 = *reinterpret_cast<const short8v*>(&stA[w][m][32 + kg * 8]);
#pragma unroll
        for (int cq = 0; cq < 4; ++cq) {
            short8v B0 = *reinterpret_cast<const short8v*>(&sWbT[(16 * cq + m) * 72 + kg * 8]);
            short8v B1 = *reinterpret_cast<const short8v*>(&sWbT[(16 * cq + m) * 72 + 32 + kg * 8]);
            float bb = sbb[16 * cq + m];
            float4v acc = {bb, bb, bb, bb};
            acc = __builtin_amdgcn_mfma_f32_16x16x32_bf16(C0, B0, acc, 0, 0, 0);
            acc = __builtin_amdgcn_mfma_f32_16x16x32_bf16(C1, B1, acc, 0, 0, 0);
#pragma unroll
            for (int i = 0; i < 4; ++i)
                h2[(size_t)(nt0 + kg * 4 + i) * 64 + 16 * cq + m] = fmaxf(acc[i], 0.0f);
        }
        __builtin_amdgcn_wave_barrier();
    }
}

// ---------------- Pool stage A: per-(graph, chunk) partial sums ----------------
__global__ __launch_bounds__(256) void poolA(const float* __restrict__ h2,
                                             const int* __restrict__ batch,
                                             float* __restrict__ partial) {  // [PCHUNK][N_GRAPHS][64]
    int g = blockIdx.x & (N_GRAPHS - 1);
    int c = blockIdx.x >> 7;

    int lo = 0, hi = N_NODES;
    while (lo < hi) { int mid = (lo + hi) >> 1; if (batch[mid] < g) lo = mid + 1; else hi = mid; }
    int start = lo;
    lo = start; hi = N_NODES;
    while (lo < hi) { int mid = (lo + hi) >> 1; if (batch[mid] < g + 1) lo = mid + 1; else hi = mid; }
    int end = lo;

    int len = end - start;
    int cs = start + (int)((long long)len * c / PCHUNK);
    int ce = start + (int)((long long)len * (c + 1) / PCHUNK);

    int j = threadIdx.x & 63;
    int r = threadIdx.x >> 6;
    float local = 0.0f;
    for (int n = cs + r; n < ce; n += 4)
        local += h2[(size_t)n * 64 + j];

    __shared__ float red[4][64];
    red[r][j] = local;
    __syncthreads();
    if (r == 0)
        partial[((size_t)c * N_GRAPHS + g) * 64 + j] = red[0][j] + red[1][j] + red[2][j] + red[3][j];
}

// ---------------- Pool stage B: reduce chunks, divide by count ----------------
__global__ __launch_bounds__(64) void poolB(const float* __restrict__ partial,
                                            const int* __restrict__ batch,
                                            float* __restrict__ out) {
    int g = blockIdx.x;
    int j = threadIdx.x;

    int lo = 0, hi = N_NODES;
    while (lo < hi) { int mid = (lo + hi) >> 1; if (batch[mid] < g) lo = mid + 1; else hi = mid; }
    int start = lo;
    lo = start; hi = N_NODES;
    while (lo < hi) { int mid = (lo + hi) >> 1; if (batch[mid] < g + 1) lo = mid + 1; else hi = mid; }
    int end = lo;

    float s = 0.0f;
#pragma unroll
    for (int c = 0; c < PCHUNK; ++c)
        s += partial[((size_t)c * N_GRAPHS + g) * 64 + j];
    float cnt = (float)((end - start) > 1 ? (end - start) : 1);
    out[g * 64 + j] = s / cnt;
}

extern "C" void kernel_launch(void* const* d_in, const int* in_sizes, int n_in,
                              void* d_out, int out_size, void* d_ws, size_t ws_size,
                              hipStream_t stream) {
    const float* x    = (const float*)d_in[0];
    const int*   ei   = (const int*)d_in[1];
    const int*   bat  = (const int*)d_in[2];
    const float* W1a  = (const float*)d_in[3];
    const float* b1a  = (const float*)d_in[4];
    const float* W1b  = (const float*)d_in[5];
    const float* b1b  = (const float*)d_in[6];
    const float* W2a  = (const float*)d_in[7];
    const float* b2a  = (const float*)d_in[8];
    const float* W2b  = (const float*)d_in[9];
    const float* b2b  = (const float*)d_in[10];
    float* out = (float*)d_out;

    const int* src = ei;
    const int* dst = ei + N_EDGES;

    char* ws = (char*)d_ws;
    auto alignup = [](size_t v) { return (v + 255) & ~(size_t)255; };
    int*   bcnt  = (int*)ws;                       ws += alignup((size_t)NBUCK * 16 * 4);
    int*   bbase = (int*)ws;                       ws += alignup((size_t)(NBUCK + 1) * 4);
    int*   off   = (int*)ws;                       ws += alignup((size_t)(N_NODES + 1) * 4);
    int*   esrc  = (int*)ws;                       ws += alignup((size_t)N_EDGES * 4);
    unsigned short* h1b = (unsigned short*)ws;     ws += alignup((size_t)N_NODES * HID * 2);
    float* partial = (float*)ws;                   ws += alignup((size_t)PCHUNK * N_GRAPHS * 64 * 4);
    // bbuf and h2 share a slab: bbuf dead before l2_mfma writes h2
    int*   bbuf  = (int*)ws;
    float* h2    = (float*)ws;

    hipMemsetAsync(bcnt, 0, (size_t)NBUCK * 16 * 4, stream);

    bucketA<<<NBLKA, BLKA, 0, stream>>>(src, dst, bcnt, bbuf);
    scanBuck<<<1, 256, 0, stream>>>(bcnt, bbase, off);
    bucketB<<<NBUCK, 1024, 0, stream>>>(bbuf, bcnt, bbase, off, esrc);

    l1_mfma<<<NBLK2, BLK2, 0, stream>>>(x, off, esrc, W1a, b1a, W1b, b1b, h1b);
    l2_mfma<<<NBLK2, BLK2, 0, stream>>>((const unsigned*)h1b, off, esrc, W2a, b2a, W2b, b2b, h2);

    poolA<<<N_GRAPHS * PCHUNK, 256, 0, stream>>>(h2, bat, partial);
    poolB<<<N_GRAPHS, 64, 0, stream>>>(partial, bat, out);
}

// Round 14
// 146.776 us; speedup vs baseline: 1.3178x; 1.0261x over previous
//
#include <hip/hip_runtime.h>
#include <hip/hip_bf16.h>

#define N_NODES  100000
#define N_EDGES  1600000
#define N_GRAPHS 128
#define HID      64
#define NBUCK    256
#define NPB      391                 // nodes per bucket: ceil(100000/256)
#define CAP      8192                // per-bucket record capacity (mean 6250)
#define BLKA     1024
#define EPTA     4
#define EPBA     (BLKA * EPTA)       // 4096 edges per pass-A block
#define NBLKA    ((N_EDGES + EPBA - 1) / EPBA)   // 391

#define NTILES   (N_NODES / 16)      // 6250 (exact)
#define BLK2     512
#define WPB2     (BLK2 / 64)         // 8 waves per block
#define NBLK2    1024                // 8192 waves
#define NWAVES2  (NBLK2 * WPB2)      // 8192
#define TCW      256                 // per-tile fixed-cost weight for balancing
#define PCHUNK   16                  // pool chunks per graph

typedef short short8v __attribute__((ext_vector_type(8)));
typedef float float4v __attribute__((ext_vector_type(4)));

__device__ __forceinline__ float bl_lo(unsigned u) { return __uint_as_float(u << 16); }
__device__ __forceinline__ float bl_hi(unsigned u) { return __uint_as_float(u & 0xffff0000u); }
__device__ __forceinline__ unsigned short f2bf(float f) {
    unsigned u = __float_as_uint(f);
    u += 0x7fffu + ((u >> 16) & 1u);           // round-to-nearest-even
    return (unsigned short)(u >> 16);
}

// ---------------- Pass A: LDS counting sort into 256 dst-range buckets; PACKED records ----------------
// rec = src | (loc << 17), loc = dst - bucket*NPB  (src < 2^17, loc < 391 < 2^9)
__global__ __launch_bounds__(1024) void bucketA(const int* __restrict__ src,
                                                const int* __restrict__ dst,
                                                int* __restrict__ bcnt,      // [NBUCK*16], line-padded
                                                int* __restrict__ bbuf) {    // [NBUCK*CAP] packed
    __shared__ int cnt[NBUCK], scn[NBUCK], cur[NBUCK], gb[NBUCK];
    __shared__ int srt[EPBA];                     // 16 KB
    __shared__ unsigned char sbb_[EPBA];          // 4 KB: bucket id per sorted slot
    int tid = threadIdx.x;
    if (tid < NBUCK) cnt[tid] = 0;
    __syncthreads();

    int e0 = (blockIdx.x * BLKA + tid) * EPTA;
    int s[EPTA], d[EPTA], b[EPTA];
    int nv = 0;
    if (e0 + EPTA <= N_EDGES) {
        int4 s4 = *reinterpret_cast<const int4*>(src + e0);
        int4 d4 = *reinterpret_cast<const int4*>(dst + e0);
        s[0] = s4.x; s[1] = s4.y; s[2] = s4.z; s[3] = s4.w;
        d[0] = d4.x; d[1] = d4.y; d[2] = d4.z; d[3] = d4.w;
        nv = EPTA;
    } else {
        for (int e = e0; e < N_EDGES; ++e) { s[nv] = src[e]; d[nv] = dst[e]; ++nv; }
    }
    for (int k = 0; k < nv; ++k) {
        b[k] = (int)((unsigned)d[k] / (unsigned)NPB);
        atomicAdd(&cnt[b[k]], 1);
    }
    __syncthreads();

    if (tid < NBUCK) scn[tid] = cnt[tid];
    __syncthreads();
    for (int o = 1; o < NBUCK; o <<= 1) {
        int v = 0;
        if (tid < NBUCK && tid >= o) v = scn[tid - o];
        __syncthreads();
        if (tid < NBUCK && tid >= o) scn[tid] += v;
        __syncthreads();
    }
    if (tid < NBUCK) {
        int ex = scn[tid] - cnt[tid];
        cur[tid] = ex;
        gb[tid] = (cnt[tid] > 0) ? atomicAdd(&bcnt[tid * 16], cnt[tid]) : 0;
        scn[tid] = ex;
    }
    __syncthreads();

    for (int k = 0; k < nv; ++k) {
        int p = atomicAdd(&cur[b[k]], 1);
        int loc = d[k] - b[k] * NPB;
        srt[p] = s[k] | (loc << 17);
        sbb_[p] = (unsigned char)b[k];
    }
    __syncthreads();

    int tot = scn[NBUCK - 1] + cnt[NBUCK - 1];
    for (int i = tid; i < tot; i += BLKA) {
        int bb = sbb_[i];
        bbuf[(size_t)bb * CAP + gb[bb] + (i - scn[bb])] = srt[i];
    }
}

// ---------------- bucket base scan ----------------
__global__ __launch_bounds__(256) void scanBuck(const int* __restrict__ bcnt,
                                                int* __restrict__ bbase,
                                                int* __restrict__ off) {
    __shared__ int s[NBUCK];
    int t = threadIdx.x;
    int own = bcnt[t * 16];
    s[t] = own;
    __syncthreads();
    for (int o = 1; o < NBUCK; o <<= 1) {
        int v = (t >= o) ? s[t - o] : 0;
        __syncthreads();
        s[t] += v;
        __syncthreads();
    }
    bbase[t] = s[t] - own;
    if (t == NBUCK - 1) {
        bbase[NBUCK] = s[t];
        off[N_NODES] = s[t];
    }
}

// ---------------- Pass B: per-bucket CSR + FUSED x-aggregation -> esrc, off, xin ----------------
__global__ __launch_bounds__(1024) void bucketB(const int* __restrict__ bbuf,
                                                const int* __restrict__ bcnt,
                                                const int* __restrict__ bbase,
                                                const float* __restrict__ x,
                                                int* __restrict__ off,
                                                int* __restrict__ esrc,
                                                float* __restrict__ xin) {   // [N_NODES][3] = x_self + sum x_nbr
    __shared__ int hist[NPB], scn[NPB], cur[NPB];
    __shared__ float agg[NPB * 3];                // 4.7 KB
    int b = blockIdx.x, tid = threadIdx.x;
    int node0 = b * NPB;
    int ncnt = N_NODES - node0; if (ncnt > NPB) ncnt = NPB;
    if (tid < NPB) hist[tid] = 0;
    for (int i = tid; i < NPB * 3; i += 1024) agg[i] = 0.0f;
    __syncthreads();

    int cnt  = bcnt[b * 16];
    int base = bbase[b];
    const int* buf = bbuf + (size_t)b * CAP;

    for (int i = tid; i < cnt; i += 1024)
        atomicAdd(&hist[((unsigned)buf[i]) >> 17], 1);
    __syncthreads();

    if (tid < NPB) scn[tid] = hist[tid];
    __syncthreads();
    for (int o = 1; o < NPB; o <<= 1) {
        int v = 0;
        if (tid < NPB && tid >= o) v = scn[tid - o];
        __syncthreads();
        if (tid < NPB && tid >= o) scn[tid] += v;
        __syncthreads();
    }
    if (tid < ncnt) {
        int ex = scn[tid] - hist[tid];
        off[node0 + tid] = base + ex;
        cur[tid] = ex;
    }
    __syncthreads();

    for (int i = tid; i < cnt; i += 1024) {
        int rec = buf[i];
        int loc = ((unsigned)rec) >> 17;
        int s = rec & 0x1FFFF;
        int p = atomicAdd(&cur[loc], 1);
        esrc[base + p] = s;
        float x0 = x[s * 3 + 0], x1 = x[s * 3 + 1], x2 = x[s * 3 + 2];
        unsafeAtomicAdd(&agg[loc * 3 + 0], x0);
        unsafeAtomicAdd(&agg[loc * 3 + 1], x1);
        unsafeAtomicAdd(&agg[loc * 3 + 2], x2);
    }
    __syncthreads();

    for (int i = tid; i < ncnt * 3; i += 1024)
        xin[node0 * 3 + i] = x[node0 * 3 + i] + agg[i];
}

// ---------------- balanced tile partition: smallest t with off[16t]+TCW*t >= target ----------------
__device__ __forceinline__ int tile_bound(const int* __restrict__ off, long long target) {
    int lo = 0, hi = NTILES;
    while (lo < hi) {
        int mid = (lo + hi) >> 1;
        long long v = (long long)off[mid * 16] + (long long)TCW * mid;
        if (v < target) lo = mid + 1; else hi = mid;
    }
    return lo;
}

// ---------------- Layer 1: dense MLP over xin (no edge loop) -> h1 (bf16) ----------------
__global__ __launch_bounds__(512, 8) void l1_mfma(const float* __restrict__ xin,
                                                  const float* __restrict__ W1a,
                                                  const float* __restrict__ b1a,
                                                  const float* __restrict__ W1b,
                                                  const float* __restrict__ b1b,
                                                  unsigned short* __restrict__ h1b) {
    __shared__ float sWa[3 * 64];
    __shared__ float sba[64], sbb[64];
    __shared__ __align__(16) unsigned short sWbT[64 * 72];   // sWbT[n*72+k] = bf16(W1b[k][n])
    __shared__ __align__(16) unsigned short stA[WPB2][16][72];

    int tid = threadIdx.x;
    for (int i = tid; i < 3 * 64; i += BLK2) sWa[i] = W1a[i];
    for (int i = tid; i < 64 * 64; i += BLK2) {
        int k = i >> 6, n = i & 63;
        sWbT[n * 72 + k] = f2bf(W1b[i]);
    }
    if (tid < 64) { sba[tid] = b1a[tid]; sbb[tid] = b1b[tid]; }
    __syncthreads();

    int w = tid >> 6;
    int l = tid & 63;
    int m  = l & 15;          // A row / D col
    int kg = l >> 4;          // k-group / D row-group
    int wid = blockIdx.x * WPB2 + w;

    for (int t = wid; t < NTILES; t += NWAVES2) {
        int nt0 = t * 16;
#pragma unroll 4
        for (int mm = 0; mm < 16; ++mm) {
            int n = nt0 + mm;
            float in0 = xin[n * 3 + 0];
            float in1 = xin[n * 3 + 1];
            float in2 = xin[n * 3 + 2];
            float tt = sba[l] + in0 * sWa[l] + in1 * sWa[64 + l] + in2 * sWa[128 + l];
            stA[w][mm][l] = f2bf(fmaxf(tt, 0.0f));
        }
        __builtin_amdgcn_wave_barrier();

        short8v A0 = *reinterpret_cast<const short8v*>(&stA[w][m][kg * 8]);
        short8v A1 = *reinterpret_cast<const short8v*>(&stA[w][m][32 + kg * 8]);
#pragma unroll
        for (int cq = 0; cq < 4; ++cq) {
            short8v B0 = *reinterpret_cast<const short8v*>(&sWbT[(16 * cq + m) * 72 + kg * 8]);
            short8v B1 = *reinterpret_cast<const short8v*>(&sWbT[(16 * cq + m) * 72 + 32 + kg * 8]);
            float bb = sbb[16 * cq + m];
            float4v acc = {bb, bb, bb, bb};
            acc = __builtin_amdgcn_mfma_f32_16x16x32_bf16(A0, B0, acc, 0, 0, 0);
            acc = __builtin_amdgcn_mfma_f32_16x16x32_bf16(A1, B1, acc, 0, 0, 0);
#pragma unroll
            for (int i = 0; i < 4; ++i)
                h1b[(size_t)(nt0 + kg * 4 + i) * 64 + 16 * cq + m] = f2bf(fmaxf(acc[i], 0.0f));
        }
        __builtin_amdgcn_wave_barrier();
    }
}

// ---------------- Layer 2: 4-slot bf16 gather + double MFMA MLP -> h2 (f32)  [R10 structure] ----------------
__global__ __launch_bounds__(512, 8) void l2_mfma(const unsigned* __restrict__ h1p,   // packed 2xbf16
                                                  const int* __restrict__ off,
                                                  const int* __restrict__ esrc,
                                                  const float* __restrict__ W2a,
                                                  const float* __restrict__ b2a,
                                                  const float* __restrict__ W2b,
                                                  const float* __restrict__ b2b,
                                                  float* __restrict__ h2) {
    __shared__ float sba[64], sbb[64];
    __shared__ __align__(16) unsigned short sWaT[64 * 72];   // sWaT[n*72+k] = bf16(W2a[k][n])
    __shared__ __align__(16) unsigned short sWbT[64 * 72];
    __shared__ __align__(16) unsigned short stA[WPB2][16][72];

    int tid = threadIdx.x;
    for (int i = tid; i < 64 * 64; i += BLK2) {
        int k = i >> 6, n = i & 63;
        sWaT[n * 72 + k] = f2bf(W2a[i]);
        sWbT[n * 72 + k] = f2bf(W2b[i]);
    }
    if (tid < 64) { sba[tid] = b2a[tid]; sbb[tid] = b2b[tid]; }
    __syncthreads();

    int w = tid >> 6;
    int l = tid & 63;
    int g = l >> 4;          // edge slot 0..3
    int q = l & 15;          // 8B chunk of 128B row
    int m  = l & 15;
    int kg = l >> 4;
    int wid = blockIdx.x * WPB2 + w;

    const long long TOT = (long long)N_EDGES + (long long)TCW * NTILES;
    int t0 = tile_bound(off, TOT * wid / NWAVES2);
    int t1 = tile_bound(off, TOT * (wid + 1) / NWAVES2);

    for (int t = t0; t < t1; ++t) {
        int nt0 = t * 16;
        // ---- gather 16 nodes -> stA rows (bf16) ----
        for (int mm = 0; mm < 16; ++mm) {
            int n = nt0 + mm;
            int start = off[n], end = off[n + 1];
            int em = max(end - 1, 0);
            float a0 = 0.f, a1 = 0.f, a2 = 0.f, a3 = 0.f;
            if (g == 0) {      // self term once
                uint2 v = *reinterpret_cast<const uint2*>(h1p + (size_t)n * 32 + 2 * q);
                a0 += bl_lo(v.x); a1 += bl_hi(v.x); a2 += bl_lo(v.y); a3 += bl_hi(v.y);
            }
            for (int e = start; e < end; e += 16) {
                int tA = e + g, tB = e + 4 + g, tC = e + 8 + g, tD = e + 12 + g;
                int iA = min(tA, em);
                int iB = min(tB, em);
                int iC = min(tC, em);
                int iD = min(tD, em);
                int sa = esrc[iA], sb = esrc[iB], sc = esrc[iC], sd = esrc[iD];
                uint2 vA = *reinterpret_cast<const uint2*>(h1p + (size_t)sa * 32 + 2 * q);
                uint2 vB = *reinterpret_cast<const uint2*>(h1p + (size_t)sb * 32 + 2 * q);
                uint2 vC = *reinterpret_cast<const uint2*>(h1p + (size_t)sc * 32 + 2 * q);
                uint2 vD = *reinterpret_cast<const uint2*>(h1p + (size_t)sd * 32 + 2 * q);
                unsigned mA = tA < end ? 0xffffffffu : 0u;
                unsigned mB = tB < end ? 0xffffffffu : 0u;
                unsigned mC = tC < end ? 0xffffffffu : 0u;
                unsigned mD = tD < end ? 0xffffffffu : 0u;
                a0 += (bl_lo(vA.x & mA) + bl_lo(vB.x & mB)) + (bl_lo(vC.x & mC) + bl_lo(vD.x & mD));
                a1 += (bl_hi(vA.x & mA) + bl_hi(vB.x & mB)) + (bl_hi(vC.x & mC) + bl_hi(vD.x & mD));
                a2 += (bl_lo(vA.y & mA) + bl_lo(vB.y & mB)) + (bl_lo(vC.y & mC) + bl_lo(vD.y & mD));
                a3 += (bl_hi(vA.y & mA) + bl_hi(vB.y & mB)) + (bl_hi(vC.y & mC) + bl_hi(vD.y & mD));
            }
            a0 += __shfl_xor(a0, 16); a0 += __shfl_xor(a0, 32);
            a1 += __shfl_xor(a1, 16); a1 += __shfl_xor(a1, 32);
            a2 += __shfl_xor(a2, 16); a2 += __shfl_xor(a2, 32);
            a3 += __shfl_xor(a3, 16); a3 += __shfl_xor(a3, 32);
            if (g == 0) {
                uint2 pk;
                pk.x = ((unsigned)f2bf(a1) << 16) | (unsigned)f2bf(a0);
                pk.y = ((unsigned)f2bf(a3) << 16) | (unsigned)f2bf(a2);
                *reinterpret_cast<uint2*>(&stA[w][mm][4 * q]) = pk;
            }
        }
        __builtin_amdgcn_wave_barrier();

        // ---- matmul1: relu(agg @ W2a + b2a), restage as bf16 ----
        short8v A0 = *reinterpret_cast<const short8v*>(&stA[w][m][kg * 8]);
        short8v A1 = *reinterpret_cast<const short8v*>(&stA[w][m][32 + kg * 8]);
#pragma unroll
        for (int cq = 0; cq < 4; ++cq) {
            short8v B0 = *reinterpret_cast<const short8v*>(&sWaT[(16 * cq + m) * 72 + kg * 8]);
            short8v B1 = *reinterpret_cast<const short8v*>(&sWaT[(16 * cq + m) * 72 + 32 + kg * 8]);
            float bb = sba[16 * cq + m];
            float4v acc = {bb, bb, bb, bb};
            acc = __builtin_amdgcn_mfma_f32_16x16x32_bf16(A0, B0, acc, 0, 0, 0);
            acc = __builtin_amdgcn_mfma_f32_16x16x32_bf16(A1, B1, acc, 0, 0, 0);
#pragma unroll
            for (int i = 0; i < 4; ++i)
                stA[w][kg * 4 + i][16 * cq + m] = f2bf(fmaxf(acc[i], 0.0f));
        }
        __builtin_amdgcn_wave_barrier();

        // ---- matmul2: relu(h @ W2b + b2b) -> h2 ----
        short8v C0 = *reinterpret_cast<const short8v*>(&stA[w][m][kg * 8]);
        short8v C1 = *reinterpret_cast<const short8v*>(&stA[w][m][32 + kg * 8]);
#pragma unroll
        for (int cq = 0; cq < 4; ++cq) {
            short8v B0 = *reinterpret_cast<const short8v*>(&sWbT[(16 * cq + m) * 72 + kg * 8]);
            short8v B1 = *reinterpret_cast<const short8v*>(&sWbT[(16 * cq + m) * 72 + 32 + kg * 8]);
            float bb = sbb[16 * cq + m];
            float4v acc = {bb, bb, bb, bb};
            acc = __builtin_amdgcn_mfma_f32_16x16x32_bf16(C0, B0, acc, 0, 0, 0);
            acc = __builtin_amdgcn_mfma_f32_16x16x32_bf16(C1, B1, acc, 0, 0, 0);
#pragma unroll
            for (int i = 0; i < 4; ++i)
                h2[(size_t)(nt0 + kg * 4 + i) * 64 + 16 * cq + m] = fmaxf(acc[i], 0.0f);
        }
        __builtin_amdgcn_wave_barrier();
    }
}

// ---------------- Pool stage A: per-(graph, chunk) partial sums ----------------
__global__ __launch_bounds__(256) void poolA(const float* __restrict__ h2,
                                             const int* __restrict__ batch,
                                             float* __restrict__ partial) {  // [PCHUNK][N_GRAPHS][64]
    int g = blockIdx.x & (N_GRAPHS - 1);
    int c = blockIdx.x >> 7;

    int lo = 0, hi = N_NODES;
    while (lo < hi) { int mid = (lo + hi) >> 1; if (batch[mid] < g) lo = mid + 1; else hi = mid; }
    int start = lo;
    lo = start; hi = N_NODES;
    while (lo < hi) { int mid = (lo + hi) >> 1; if (batch[mid] < g + 1) lo = mid + 1; else hi = mid; }
    int end = lo;

    int len = end - start;
    int cs = start + (int)((long long)len * c / PCHUNK);
    int ce = start + (int)((long long)len * (c + 1) / PCHUNK);

    int j = threadIdx.x & 63;
    int r = threadIdx.x >> 6;
    float local = 0.0f;
    for (int n = cs + r; n < ce; n += 4)
        local += h2[(size_t)n * 64 + j];

    __shared__ float red[4][64];
    red[r][j] = local;
    __syncthreads();
    if (r == 0)
        partial[((size_t)c * N_GRAPHS + g) * 64 + j] = red[0][j] + red[1][j] + red[2][j] + red[3][j];
}

// ---------------- Pool stage B: reduce chunks, divide by count ----------------
__global__ __launch_bounds__(64) void poolB(const float* __restrict__ partial,
                                            const int* __restrict__ batch,
                                            float* __restrict__ out) {
    int g = blockIdx.x;
    int j = threadIdx.x;

    int lo = 0, hi = N_NODES;
    while (lo < hi) { int mid = (lo + hi) >> 1; if (batch[mid] < g) lo = mid + 1; else hi = mid; }
    int start = lo;
    lo = start; hi = N_NODES;
    while (lo < hi) { int mid = (lo + hi) >> 1; if (batch[mid] < g + 1) lo = mid + 1; else hi = mid; }
    int end = lo;

    float s = 0.0f;
#pragma unroll
    for (int c = 0; c < PCHUNK; ++c)
        s += partial[((size_t)c * N_GRAPHS + g) * 64 + j];
    float cnt = (float)((end - start) > 1 ? (end - start) : 1);
    out[g * 64 + j] = s / cnt;
}

extern "C" void kernel_launch(void* const* d_in, const int* in_sizes, int n_in,
                              void* d_out, int out_size, void* d_ws, size_t ws_size,
                              hipStream_t stream) {
    const float* x    = (const float*)d_in[0];
    const int*   ei   = (const int*)d_in[1];
    const int*   bat  = (const int*)d_in[2];
    const float* W1a  = (const float*)d_in[3];
    const float* b1a  = (const float*)d_in[4];
    const float* W1b  = (const float*)d_in[5];
    const float* b1b  = (const float*)d_in[6];
    const float* W2a  = (const float*)d_in[7];
    const float* b2a  = (const float*)d_in[8];
    const float* W2b  = (const float*)d_in[9];
    const float* b2b  = (const float*)d_in[10];
    float* out = (float*)d_out;

    const int* src = ei;
    const int* dst = ei + N_EDGES;

    char* ws = (char*)d_ws;
    auto alignup = [](size_t v) { return (v + 255) & ~(size_t)255; };
    int*   bcnt  = (int*)ws;                       ws += alignup((size_t)NBUCK * 16 * 4);
    int*   bbase = (int*)ws;                       ws += alignup((size_t)(NBUCK + 1) * 4);
    int*   off   = (int*)ws;                       ws += alignup((size_t)(N_NODES + 1) * 4);
    int*   esrc  = (int*)ws;                       ws += alignup((size_t)N_EDGES * 4);
    float* xin   = (float*)ws;                     ws += alignup((size_t)N_NODES * 3 * 4);
    unsigned short* h1b = (unsigned short*)ws;     ws += alignup((size_t)N_NODES * HID * 2);
    float* partial = (float*)ws;                   ws += alignup((size_t)PCHUNK * N_GRAPHS * 64 * 4);
    // bbuf and h2 share a slab: bbuf dead before l2_mfma writes h2
    int*   bbuf  = (int*)ws;
    float* h2    = (float*)ws;

    hipMemsetAsync(bcnt, 0, (size_t)NBUCK * 16 * 4, stream);

    bucketA<<<NBLKA, BLKA, 0, stream>>>(src, dst, bcnt, bbuf);
    scanBuck<<<1, 256, 0, stream>>>(bcnt, bbase, off);
    bucketB<<<NBUCK, 1024, 0, stream>>>(bbuf, bcnt, bbase, x, off, esrc, xin);

    l1_mfma<<<NBLK2, BLK2, 0, stream>>>(xin, W1a, b1a, W1b, b1b, h1b);
    l2_mfma<<<NBLK2, BLK2, 0, stream>>>((const unsigned*)h1b, off, esrc, W2a, b2a, W2b, b2b, h2);

    poolA<<<N_GRAPHS * PCHUNK, 256, 0, stream>>>(h2, bat, partial);
    poolB<<<N_GRAPHS, 64, 0, stream>>>(partial, bat, out);
}

// Round 15
// 143.826 us; speedup vs baseline: 1.3449x; 1.0205x over previous
//
#include <hip/hip_runtime.h>
#include <hip/hip_bf16.h>

#define N_NODES  100000
#define N_EDGES  1600000
#define N_GRAPHS 128
#define HID      64
#define NBUCK    256
#define NPB      391                 // nodes per bucket: ceil(100000/256)
#define CAP      8192                // per-bucket record capacity (mean 6250, sd ~79)
#define BLKA     1024
#define EPTA     4
#define EPBA     (BLKA * EPTA)       // 4096 edges per pass-A block
#define NBLKA    ((N_EDGES + EPBA - 1) / EPBA)   // 391

#define NTILES   (N_NODES / 16)      // 6250 (exact)
#define BLK2     512
#define WPB2     (BLK2 / 64)         // 8 waves per block
#define NBLK2    1024                // 8192 waves
#define NWAVES2  (NBLK2 * WPB2)      // 8192
#define TCW      256                 // per-tile fixed-cost weight for balancing
#define PCHUNK   16                  // pool chunks per graph

typedef short short8v __attribute__((ext_vector_type(8)));
typedef float float4v __attribute__((ext_vector_type(4)));

__device__ __forceinline__ float bl_lo(unsigned u) { return __uint_as_float(u << 16); }
__device__ __forceinline__ float bl_hi(unsigned u) { return __uint_as_float(u & 0xffff0000u); }
__device__ __forceinline__ unsigned short f2bf(float f) {
    unsigned u = __float_as_uint(f);
    u += 0x7fffu + ((u >> 16) & 1u);           // round-to-nearest-even
    return (unsigned short)(u >> 16);
}

// ---------------- Pass A: LDS counting sort into 256 dst-range buckets; PACKED records ----------------
// rec = src | (loc << 17), loc = dst - bucket*NPB  (src < 2^17, loc < 391 < 2^9)
__global__ __launch_bounds__(1024) void bucketA(const int* __restrict__ src,
                                                const int* __restrict__ dst,
                                                int* __restrict__ bcnt,      // [NBUCK*16], line-padded
                                                int* __restrict__ bbuf) {    // [NBUCK*CAP] packed
    __shared__ int cnt[NBUCK], scn[NBUCK], cur[NBUCK], gb[NBUCK];
    __shared__ int srt[EPBA];                     // 16 KB
    __shared__ unsigned char sbb_[EPBA];          // 4 KB: bucket id per sorted slot
    int tid = threadIdx.x;
    if (tid < NBUCK) cnt[tid] = 0;
    __syncthreads();

    int e0 = (blockIdx.x * BLKA + tid) * EPTA;
    int s[EPTA], d[EPTA], b[EPTA];
    int nv = 0;
    if (e0 + EPTA <= N_EDGES) {
        int4 s4 = *reinterpret_cast<const int4*>(src + e0);
        int4 d4 = *reinterpret_cast<const int4*>(dst + e0);
        s[0] = s4.x; s[1] = s4.y; s[2] = s4.z; s[3] = s4.w;
        d[0] = d4.x; d[1] = d4.y; d[2] = d4.z; d[3] = d4.w;
        nv = EPTA;
    } else {
        for (int e = e0; e < N_EDGES; ++e) { s[nv] = src[e]; d[nv] = dst[e]; ++nv; }
    }
    for (int k = 0; k < nv; ++k) {
        b[k] = (int)((unsigned)d[k] / (unsigned)NPB);
        atomicAdd(&cnt[b[k]], 1);
    }
    __syncthreads();

    if (tid < NBUCK) scn[tid] = cnt[tid];
    __syncthreads();
    for (int o = 1; o < NBUCK; o <<= 1) {
        int v = 0;
        if (tid < NBUCK && tid >= o) v = scn[tid - o];
        __syncthreads();
        if (tid < NBUCK && tid >= o) scn[tid] += v;
        __syncthreads();
    }
    if (tid < NBUCK) {
        int ex = scn[tid] - cnt[tid];
        cur[tid] = ex;
        gb[tid] = (cnt[tid] > 0) ? atomicAdd(&bcnt[tid * 16], cnt[tid]) : 0;
        scn[tid] = ex;
    }
    __syncthreads();

    for (int k = 0; k < nv; ++k) {
        int p = atomicAdd(&cur[b[k]], 1);
        int loc = d[k] - b[k] * NPB;
        srt[p] = s[k] | (loc << 17);
        sbb_[p] = (unsigned char)b[k];
    }
    __syncthreads();

    int tot = scn[NBUCK - 1] + cnt[NBUCK - 1];
    for (int i = tid; i < tot; i += BLKA) {
        int bb = sbb_[i];
        bbuf[(size_t)bb * CAP + gb[bb] + (i - scn[bb])] = srt[i];
    }
}

// ---------------- bucket base scan ----------------
__global__ __launch_bounds__(256) void scanBuck(const int* __restrict__ bcnt,
                                                int* __restrict__ bbase,
                                                int* __restrict__ off) {
    __shared__ int s[NBUCK];
    int t = threadIdx.x;
    int own = bcnt[t * 16];
    s[t] = own;
    __syncthreads();
    for (int o = 1; o < NBUCK; o <<= 1) {
        int v = (t >= o) ? s[t - o] : 0;
        __syncthreads();
        s[t] += v;
        __syncthreads();
    }
    bbase[t] = s[t] - own;
    if (t == NBUCK - 1) {
        bbase[NBUCK] = s[t];
        off[N_NODES] = s[t];
    }
}

// ---------------- Pass B (fused): single-pass CSR + x-agg + layer-1 MLP -> esrc, off, h1b ----------------
__global__ __launch_bounds__(1024) void bucketB(const int* __restrict__ bbuf,
                                                const int* __restrict__ bcnt,
                                                const int* __restrict__ bbase,
                                                const float* __restrict__ x,
                                                const float* __restrict__ W1a,
                                                const float* __restrict__ b1a,
                                                const float* __restrict__ W1b,
                                                const float* __restrict__ b1b,
                                                int* __restrict__ off,
                                                int* __restrict__ esrc,
                                                unsigned short* __restrict__ h1b) {
    __shared__ int hist[NPB], scn[NPB], cur[NPB];     // 4.7 KB
    __shared__ float agg[NPB * 3];                    // 4.7 KB  (becomes xin)
    __shared__ float sWa[3 * 64];                     // 0.75 KB
    __shared__ float sba[64], sbb[64];                // 0.5 KB
    __shared__ __align__(16) unsigned short sWbT[64 * 72];          // 9.2 KB
    __shared__ __align__(16) unsigned short stA[16][16][72];        // 36.9 KB  -> ~57 KB total

    int b = blockIdx.x, tid = threadIdx.x;
    int node0 = b * NPB;
    int ncnt = N_NODES - node0; if (ncnt > NPB) ncnt = NPB;

    // weights + zero-init
    for (int i = tid; i < 3 * 64; i += 1024) sWa[i] = W1a[i];
    for (int i = tid; i < 64 * 64; i += 1024) {
        int k = i >> 6, n = i & 63;
        sWbT[n * 72 + k] = f2bf(W1b[i]);
    }
    if (tid < 64) { sba[tid] = b1a[tid]; sbb[tid] = b1b[tid]; }
    if (tid < NPB) hist[tid] = 0;
    for (int i = tid; i < NPB * 3; i += 1024) agg[i] = 0.0f;
    __syncthreads();

    int cnt  = bcnt[b * 16];
    int base = bbase[b];
    const int* buf = bbuf + (size_t)b * CAP;

    // single coalesced read of records into registers; hist from registers
    int rec[8];
#pragma unroll
    for (int k = 0; k < 8; ++k) {
        int i = tid + k * 1024;
        rec[k] = (i < cnt) ? buf[i] : -1;
    }
#pragma unroll
    for (int k = 0; k < 8; ++k)
        if (rec[k] >= 0) atomicAdd(&hist[((unsigned)rec[k]) >> 17], 1);
    __syncthreads();

    if (tid < NPB) scn[tid] = hist[tid];
    __syncthreads();
    for (int o = 1; o < NPB; o <<= 1) {
        int v = 0;
        if (tid < NPB && tid >= o) v = scn[tid - o];
        __syncthreads();
        if (tid < NPB && tid >= o) scn[tid] += v;
        __syncthreads();
    }
    if (tid < ncnt) {
        int ex = scn[tid] - hist[tid];
        off[node0 + tid] = base + ex;
        cur[tid] = ex;
    }
    __syncthreads();

    // scatter from registers + x-aggregation into LDS
#pragma unroll
    for (int k = 0; k < 8; ++k) {
        if (rec[k] >= 0) {
            int loc = ((unsigned)rec[k]) >> 17;
            int s = rec[k] & 0x1FFFF;
            int p = atomicAdd(&cur[loc], 1);
            esrc[base + p] = s;
            float x0 = x[s * 3 + 0], x1 = x[s * 3 + 1], x2 = x[s * 3 + 2];
            unsafeAtomicAdd(&agg[loc * 3 + 0], x0);
            unsafeAtomicAdd(&agg[loc * 3 + 1], x1);
            unsafeAtomicAdd(&agg[loc * 3 + 2], x2);
        }
    }
    __syncthreads();

    // xin = x_self + agg (in place)
    for (int i = tid; i < ncnt * 3; i += 1024)
        agg[i] += x[node0 * 3 + i];
    __syncthreads();

    // fused layer-1 MLP: 16-node tiles per wave
    int w = tid >> 6, l = tid & 63;
    int m  = l & 15;
    int kg = l >> 4;
    int ntiles = (ncnt + 15) / 16;    // 25 for full buckets
    for (int t = w; t < ntiles; t += 16) {
        int nl0 = t * 16;
#pragma unroll 4
        for (int mm = 0; mm < 16; ++mm) {
            int nl = nl0 + mm;
            float tt = 0.0f;
            if (nl < ncnt) {
                float in0 = agg[nl * 3 + 0];
                float in1 = agg[nl * 3 + 1];
                float in2 = agg[nl * 3 + 2];
                tt = fmaxf(sba[l] + in0 * sWa[l] + in1 * sWa[64 + l] + in2 * sWa[128 + l], 0.0f);
            }
            stA[w][mm][l] = f2bf(tt);
        }
        __builtin_amdgcn_wave_barrier();

        short8v A0 = *reinterpret_cast<const short8v*>(&stA[w][m][kg * 8]);
        short8v A1 = *reinterpret_cast<const short8v*>(&stA[w][m][32 + kg * 8]);
#pragma unroll
        for (int cq = 0; cq < 4; ++cq) {
            short8v B0 = *reinterpret_cast<const short8v*>(&sWbT[(16 * cq + m) * 72 + kg * 8]);
            short8v B1 = *reinterpret_cast<const short8v*>(&sWbT[(16 * cq + m) * 72 + 32 + kg * 8]);
            float bb = sbb[16 * cq + m];
            float4v acc = {bb, bb, bb, bb};
            acc = __builtin_amdgcn_mfma_f32_16x16x32_bf16(A0, B0, acc, 0, 0, 0);
            acc = __builtin_amdgcn_mfma_f32_16x16x32_bf16(A1, B1, acc, 0, 0, 0);
#pragma unroll
            for (int i = 0; i < 4; ++i) {
                int nl = nl0 + kg * 4 + i;
                if (nl < ncnt)
                    h1b[(size_t)(node0 + nl) * 64 + 16 * cq + m] = f2bf(fmaxf(acc[i], 0.0f));
            }
        }
        __builtin_amdgcn_wave_barrier();
    }
}

// ---------------- balanced tile partition: smallest t with off[16t]+TCW*t >= target ----------------
__device__ __forceinline__ int tile_bound(const int* __restrict__ off, long long target) {
    int lo = 0, hi = NTILES;
    while (lo < hi) {
        int mid = (lo + hi) >> 1;
        long long v = (long long)off[mid * 16] + (long long)TCW * mid;
        if (v < target) lo = mid + 1; else hi = mid;
    }
    return lo;
}

// ---------------- Layer 2: 4-slot bf16 gather + double MFMA MLP -> h2 (f32) ----------------
__global__ __launch_bounds__(512, 8) void l2_mfma(const unsigned* __restrict__ h1p,   // packed 2xbf16
                                                  const int* __restrict__ off,
                                                  const int* __restrict__ esrc,
                                                  const float* __restrict__ W2a,
                                                  const float* __restrict__ b2a,
                                                  const float* __restrict__ W2b,
                                                  const float* __restrict__ b2b,
                                                  float* __restrict__ h2) {
    __shared__ float sba[64], sbb[64];
    __shared__ __align__(16) unsigned short sWaT[64 * 72];   // sWaT[n*72+k] = bf16(W2a[k][n])
    __shared__ __align__(16) unsigned short sWbT[64 * 72];
    __shared__ __align__(16) unsigned short stA[WPB2][16][72];

    int tid = threadIdx.x;
    for (int i = tid; i < 64 * 64; i += BLK2) {
        int k = i >> 6, n = i & 63;
        sWaT[n * 72 + k] = f2bf(W2a[i]);
        sWbT[n * 72 + k] = f2bf(W2b[i]);
    }
    if (tid < 64) { sba[tid] = b2a[tid]; sbb[tid] = b2b[tid]; }
    __syncthreads();

    int w = tid >> 6;
    int l = tid & 63;
    int g = l >> 4;          // edge slot 0..3
    int q = l & 15;          // 8B chunk of 128B row
    int m  = l & 15;
    int kg = l >> 4;
    int wid = blockIdx.x * WPB2 + w;

    const long long TOT = (long long)N_EDGES + (long long)TCW * NTILES;
    int t0 = tile_bound(off, TOT * wid / NWAVES2);
    int t1 = tile_bound(off, TOT * (wid + 1) / NWAVES2);

    for (int t = t0; t < t1; ++t) {
        int nt0 = t * 16;
        // ---- gather 16 nodes -> stA rows (bf16) ----
        for (int mm = 0; mm < 16; ++mm) {
            int n = nt0 + mm;
            int start = off[n], end = off[n + 1];
            int em = max(end - 1, 0);
            float a0 = 0.f, a1 = 0.f, a2 = 0.f, a3 = 0.f;
            if (g == 0) {      // self term once
                uint2 v = *reinterpret_cast<const uint2*>(h1p + (size_t)n * 32 + 2 * q);
                a0 += bl_lo(v.x); a1 += bl_hi(v.x); a2 += bl_lo(v.y); a3 += bl_hi(v.y);
            }
            for (int e = start; e < end; e += 16) {
                int tA = e + g, tB = e + 4 + g, tC = e + 8 + g, tD = e + 12 + g;
                int iA = min(tA, em);
                int iB = min(tB, em);
                int iC = min(tC, em);
                int iD = min(tD, em);
                int sa = esrc[iA], sb = esrc[iB], sc = esrc[iC], sd = esrc[iD];
                uint2 vA = *reinterpret_cast<const uint2*>(h1p + (size_t)sa * 32 + 2 * q);
                uint2 vB = *reinterpret_cast<const uint2*>(h1p + (size_t)sb * 32 + 2 * q);
                uint2 vC = *reinterpret_cast<const uint2*>(h1p + (size_t)sc * 32 + 2 * q);
                uint2 vD = *reinterpret_cast<const uint2*>(h1p + (size_t)sd * 32 + 2 * q);
                unsigned mA = tA < end ? 0xffffffffu : 0u;
                unsigned mB = tB < end ? 0xffffffffu : 0u;
                unsigned mC = tC < end ? 0xffffffffu : 0u;
                unsigned mD = tD < end ? 0xffffffffu : 0u;
                a0 += (bl_lo(vA.x & mA) + bl_lo(vB.x & mB)) + (bl_lo(vC.x & mC) + bl_lo(vD.x & mD));
                a1 += (bl_hi(vA.x & mA) + bl_hi(vB.x & mB)) + (bl_hi(vC.x & mC) + bl_hi(vD.x & mD));
                a2 += (bl_lo(vA.y & mA) + bl_lo(vB.y & mB)) + (bl_lo(vC.y & mC) + bl_lo(vD.y & mD));
                a3 += (bl_hi(vA.y & mA) + bl_hi(vB.y & mB)) + (bl_hi(vC.y & mC) + bl_hi(vD.y & mD));
            }
            a0 += __shfl_xor(a0, 16); a0 += __shfl_xor(a0, 32);
            a1 += __shfl_xor(a1, 16); a1 += __shfl_xor(a1, 32);
            a2 += __shfl_xor(a2, 16); a2 += __shfl_xor(a2, 32);
            a3 += __shfl_xor(a3, 16); a3 += __shfl_xor(a3, 32);
            if (g == 0) {
                uint2 pk;
                pk.x = ((unsigned)f2bf(a1) << 16) | (unsigned)f2bf(a0);
                pk.y = ((unsigned)f2bf(a3) << 16) | (unsigned)f2bf(a2);
                *reinterpret_cast<uint2*>(&stA[w][mm][4 * q]) = pk;
            }
        }
        __builtin_amdgcn_wave_barrier();

        // ---- matmul1: relu(agg @ W2a + b2a), restage as bf16 ----
        short8v A0 = *reinterpret_cast<const short8v*>(&stA[w][m][kg * 8]);
        short8v A1 = *reinterpret_cast<const short8v*>(&stA[w][m][32 + kg * 8]);
#pragma unroll
        for (int cq = 0; cq < 4; ++cq) {
            short8v B0 = *reinterpret_cast<const short8v*>(&sWaT[(16 * cq + m) * 72 + kg * 8]);
            short8v B1 = *reinterpret_cast<const short8v*>(&sWaT[(16 * cq + m) * 72 + 32 + kg * 8]);
            float bb = sba[16 * cq + m];
            float4v acc = {bb, bb, bb, bb};
            acc = __builtin_amdgcn_mfma_f32_16x16x32_bf16(A0, B0, acc, 0, 0, 0);
            acc = __builtin_amdgcn_mfma_f32_16x16x32_bf16(A1, B1, acc, 0, 0, 0);
#pragma unroll
            for (int i = 0; i < 4; ++i)
                stA[w][kg * 4 + i][16 * cq + m] = f2bf(fmaxf(acc[i], 0.0f));
        }
        __builtin_amdgcn_wave_barrier();

        // ---- matmul2: relu(h @ W2b + b2b) -> h2 ----
        short8v C0 = *reinterpret_cast<const short8v*>(&stA[w][m][kg * 8]);
        short8v C1 = *reinterpret_cast<const short8v*>(&stA[w][m][32 + kg * 8]);
#pragma unroll
        for (int cq = 0; cq < 4; ++cq) {
            short8v B0 = *reinterpret_cast<const short8v*>(&sWbT[(16 * cq + m) * 72 + kg * 8]);
            short8v B1 = *reinterpret_cast<const short8v*>(&sWbT[(16 * cq + m) * 72 + 32 + kg * 8]);
            float bb = sbb[16 * cq + m];
            float4v acc = {bb, bb, bb, bb};
            acc = __builtin_amdgcn_mfma_f32_16x16x32_bf16(C0, B0, acc, 0, 0, 0);
            acc = __builtin_amdgcn_mfma_f32_16x16x32_bf16(C1, B1, acc, 0, 0, 0);
#pragma unroll
            for (int i = 0; i < 4; ++i)
                h2[(size_t)(nt0 + kg * 4 + i) * 64 + 16 * cq + m] = fmaxf(acc[i], 0.0f);
        }
        __builtin_amdgcn_wave_barrier();
    }
}

// ---------------- Pool stage A: per-(graph, chunk) partial sums ----------------
__global__ __launch_bounds__(256) void poolA(const float* __restrict__ h2,
                                             const int* __restrict__ batch,
                                             float* __restrict__ partial) {  // [PCHUNK][N_GRAPHS][64]
    int g = blockIdx.x & (N_GRAPHS - 1);
    int c = blockIdx.x >> 7;

    int lo = 0, hi = N_NODES;
    while (lo < hi) { int mid = (lo + hi) >> 1; if (batch[mid] < g) lo = mid + 1; else hi = mid; }
    int start = lo;
    lo = start; hi = N_NODES;
    while (lo < hi) { int mid = (lo + hi) >> 1; if (batch[mid] < g + 1) lo = mid + 1; else hi = mid; }
    int end = lo;

    int len = end - start;
    int cs = start + (int)((long long)len * c / PCHUNK);
    int ce = start + (int)((long long)len * (c + 1) / PCHUNK);

    int j = threadIdx.x & 63;
    int r = threadIdx.x >> 6;
    float local = 0.0f;
    for (int n = cs + r; n < ce; n += 4)
        local += h2[(size_t)n * 64 + j];

    __shared__ float red[4][64];
    red[r][j] = local;
    __syncthreads();
    if (r == 0)
        partial[((size_t)c * N_GRAPHS + g) * 64 + j] = red[0][j] + red[1][j] + red[2][j] + red[3][j];
}

// ---------------- Pool stage B: reduce chunks, divide by count ----------------
__global__ __launch_bounds__(64) void poolB(const float* __restrict__ partial,
                                            const int* __restrict__ batch,
                                            float* __restrict__ out) {
    int g = blockIdx.x;
    int j = threadIdx.x;

    int lo = 0, hi = N_NODES;
    while (lo < hi) { int mid = (lo + hi) >> 1; if (batch[mid] < g) lo = mid + 1; else hi = mid; }
    int start = lo;
    lo = start; hi = N_NODES;
    while (lo < hi) { int mid = (lo + hi) >> 1; if (batch[mid] < g + 1) lo = mid + 1; else hi = mid; }
    int end = lo;

    float s = 0.0f;
#pragma unroll
    for (int c = 0; c < PCHUNK; ++c)
        s += partial[((size_t)c * N_GRAPHS + g) * 64 + j];
    float cnt = (float)((end - start) > 1 ? (end - start) : 1);
    out[g * 64 + j] = s / cnt;
}

extern "C" void kernel_launch(void* const* d_in, const int* in_sizes, int n_in,
                              void* d_out, int out_size, void* d_ws, size_t ws_size,
                              hipStream_t stream) {
    const float* x    = (const float*)d_in[0];
    const int*   ei   = (const int*)d_in[1];
    const int*   bat  = (const int*)d_in[2];
    const float* W1a  = (const float*)d_in[3];
    const float* b1a  = (const float*)d_in[4];
    const float* W1b  = (const float*)d_in[5];
    const float* b1b  = (const float*)d_in[6];
    const float* W2a  = (const float*)d_in[7];
    const float* b2a  = (const float*)d_in[8];
    const float* W2b  = (const float*)d_in[9];
    const float* b2b  = (const float*)d_in[10];
    float* out = (float*)d_out;

    const int* src = ei;
    const int* dst = ei + N_EDGES;

    char* ws = (char*)d_ws;
    auto alignup = [](size_t v) { return (v + 255) & ~(size_t)255; };
    int*   bcnt  = (int*)ws;                       ws += alignup((size_t)NBUCK * 16 * 4);
    int*   bbase = (int*)ws;                       ws += alignup((size_t)(NBUCK + 1) * 4);
    int*   off   = (int*)ws;                       ws += alignup((size_t)(N_NODES + 1) * 4);
    int*   esrc  = (int*)ws;                       ws += alignup((size_t)N_EDGES * 4);
    unsigned short* h1b = (unsigned short*)ws;     ws += alignup((size_t)N_NODES * HID * 2);
    float* partial = (float*)ws;                   ws += alignup((size_t)PCHUNK * N_GRAPHS * 64 * 4);
    // bbuf and h2 share a slab: bbuf dead before l2_mfma writes h2
    int*   bbuf  = (int*)ws;
    float* h2    = (float*)ws;

    hipMemsetAsync(bcnt, 0, (size_t)NBUCK * 16 * 4, stream);

    bucketA<<<NBLKA, BLKA, 0, stream>>>(src, dst, bcnt, bbuf);
    scanBuck<<<1, 256, 0, stream>>>(bcnt, bbase, off);
    bucketB<<<NBUCK, 1024, 0, stream>>>(bbuf, bcnt, bbase, x, W1a, b1a, W1b, b1b, off, esrc, h1b);

    l2_mfma<<<NBLK2, BLK2, 0, stream>>>((const unsigned*)h1b, off, esrc, W2a, b2a, W2b, b2b, h2);

    poolA<<<N_GRAPHS * PCHUNK, 256, 0, stream>>>(h2, bat, partial);
    poolB<<<N_GRAPHS, 64, 0, stream>>>(partial, bat, out);
}

// Round 16
// 132.967 us; speedup vs baseline: 1.4547x; 1.0817x over previous
//
#include <hip/hip_runtime.h>
#include <hip/hip_bf16.h>

#define N_NODES  100000
#define N_EDGES  1600000
#define N_GRAPHS 128
#define HID      64
#define NBUCK    256
#define NPB      391                 // nodes per bucket: ceil(100000/256)
#define CAP      8192                // per-bucket record capacity (mean 6250, sd ~79)
#define BLKA     1024
#define EPTA     4
#define EPBA     (BLKA * EPTA)       // 4096 edges per pass-A block
#define NBLKA    ((N_EDGES + EPBA - 1) / EPBA)   // 391

#define NTILES   (N_NODES / 16)      // 6250 (exact)
#define BLK2     512
#define WPB2     (BLK2 / 64)         // 8 waves per block
#define NBLK2    1024                // 8192 waves
#define NWAVES2  (NBLK2 * WPB2)      // 8192
#define TCW      256                 // per-tile fixed-cost weight for balancing

typedef short short8v __attribute__((ext_vector_type(8)));
typedef float float4v __attribute__((ext_vector_type(4)));

__device__ __forceinline__ float bl_lo(unsigned u) { return __uint_as_float(u << 16); }
__device__ __forceinline__ float bl_hi(unsigned u) { return __uint_as_float(u & 0xffff0000u); }
__device__ __forceinline__ unsigned short f2bf(float f) {
    unsigned u = __float_as_uint(f);
    u += 0x7fffu + ((u >> 16) & 1u);           // round-to-nearest-even
    return (unsigned short)(u >> 16);
}

// ---------------- Pass A: LDS counting sort into 256 dst-range buckets; PACKED records ----------------
// rec = src | (loc << 17), loc = dst - bucket*NPB  (src < 2^17, loc < 391 < 2^9)
__global__ __launch_bounds__(1024) void bucketA(const int* __restrict__ src,
                                                const int* __restrict__ dst,
                                                int* __restrict__ bcnt,      // [NBUCK*16], line-padded
                                                int* __restrict__ bbuf) {    // [NBUCK*CAP] packed
    __shared__ int cnt[NBUCK], scn[NBUCK], cur[NBUCK], gb[NBUCK];
    __shared__ int srt[EPBA];                     // 16 KB
    __shared__ unsigned char sbb_[EPBA];          // 4 KB: bucket id per sorted slot
    int tid = threadIdx.x;
    if (tid < NBUCK) cnt[tid] = 0;
    __syncthreads();

    int e0 = (blockIdx.x * BLKA + tid) * EPTA;
    int s[EPTA], d[EPTA], b[EPTA];
    int nv = 0;
    if (e0 + EPTA <= N_EDGES) {
        int4 s4 = *reinterpret_cast<const int4*>(src + e0);
        int4 d4 = *reinterpret_cast<const int4*>(dst + e0);
        s[0] = s4.x; s[1] = s4.y; s[2] = s4.z; s[3] = s4.w;
        d[0] = d4.x; d[1] = d4.y; d[2] = d4.z; d[3] = d4.w;
        nv = EPTA;
    } else {
        for (int e = e0; e < N_EDGES; ++e) { s[nv] = src[e]; d[nv] = dst[e]; ++nv; }
    }
    for (int k = 0; k < nv; ++k) {
        b[k] = (int)((unsigned)d[k] / (unsigned)NPB);
        atomicAdd(&cnt[b[k]], 1);
    }
    __syncthreads();

    if (tid < NBUCK) scn[tid] = cnt[tid];
    __syncthreads();
    for (int o = 1; o < NBUCK; o <<= 1) {
        int v = 0;
        if (tid < NBUCK && tid >= o) v = scn[tid - o];
        __syncthreads();
        if (tid < NBUCK && tid >= o) scn[tid] += v;
        __syncthreads();
    }
    if (tid < NBUCK) {
        int ex = scn[tid] - cnt[tid];
        cur[tid] = ex;
        gb[tid] = (cnt[tid] > 0) ? atomicAdd(&bcnt[tid * 16], cnt[tid]) : 0;
        scn[tid] = ex;
    }
    __syncthreads();

    for (int k = 0; k < nv; ++k) {
        int p = atomicAdd(&cur[b[k]], 1);
        int loc = d[k] - b[k] * NPB;
        srt[p] = s[k] | (loc << 17);
        sbb_[p] = (unsigned char)b[k];
    }
    __syncthreads();

    int tot = scn[NBUCK - 1] + cnt[NBUCK - 1];
    for (int i = tid; i < tot; i += BLKA) {
        int bb = sbb_[i];
        bbuf[(size_t)bb * CAP + gb[bb] + (i - scn[bb])] = srt[i];
    }
}

// ---------------- Pass B (fused): per-block bcnt scan + single-pass CSR + x-agg + layer-1 MLP ----------------
__global__ __launch_bounds__(1024) void bucketB(const int* __restrict__ bbuf,
                                                const int* __restrict__ bcnt,
                                                const float* __restrict__ x,
                                                const float* __restrict__ W1a,
                                                const float* __restrict__ b1a,
                                                const float* __restrict__ W1b,
                                                const float* __restrict__ b1b,
                                                int* __restrict__ off,
                                                int* __restrict__ esrc,
                                                unsigned short* __restrict__ h1b) {
    __shared__ int sb[NBUCK];                         // 1 KB: bcnt inclusive scan
    __shared__ int hist[NPB], scn[NPB], cur[NPB];     // 4.7 KB
    __shared__ float agg[NPB * 3];                    // 4.7 KB  (becomes xin)
    __shared__ float sWa[3 * 64];                     // 0.75 KB
    __shared__ float sba[64], sbb[64];                // 0.5 KB
    __shared__ __align__(16) unsigned short sWbT[64 * 72];          // 9.2 KB
    __shared__ __align__(16) unsigned short stA[16][16][72];        // 36.9 KB

    int b = blockIdx.x, tid = threadIdx.x;
    int node0 = b * NPB;
    int ncnt = N_NODES - node0; if (ncnt > NPB) ncnt = NPB;

    // weights + zero-init + bcnt scan
    for (int i = tid; i < 3 * 64; i += 1024) sWa[i] = W1a[i];
    for (int i = tid; i < 64 * 64; i += 1024) {
        int k = i >> 6, n = i & 63;
        sWbT[n * 72 + k] = f2bf(W1b[i]);
    }
    if (tid < 64) { sba[tid] = b1a[tid]; sbb[tid] = b1b[tid]; }
    if (tid < NPB) hist[tid] = 0;
    for (int i = tid; i < NPB * 3; i += 1024) agg[i] = 0.0f;
    if (tid < NBUCK) sb[tid] = bcnt[tid * 16];
    __syncthreads();
    for (int o = 1; o < NBUCK; o <<= 1) {
        int v = 0;
        if (tid < NBUCK && tid >= o) v = sb[tid - o];
        __syncthreads();
        if (tid < NBUCK && tid >= o) sb[tid] += v;
        __syncthreads();
    }
    int cnt  = bcnt[b * 16];
    int base = (b == 0) ? 0 : sb[b - 1];
    if (b == NBUCK - 1 && tid == 0) off[N_NODES] = sb[NBUCK - 1];

    const int* buf = bbuf + (size_t)b * CAP;

    // single coalesced read of records into registers; hist from registers
    int rec[8];
#pragma unroll
    for (int k = 0; k < 8; ++k) {
        int i = tid + k * 1024;
        rec[k] = (i < cnt) ? buf[i] : -1;
    }
#pragma unroll
    for (int k = 0; k < 8; ++k)
        if (rec[k] >= 0) atomicAdd(&hist[((unsigned)rec[k]) >> 17], 1);
    __syncthreads();

    if (tid < NPB) scn[tid] = hist[tid];
    __syncthreads();
    for (int o = 1; o < NPB; o <<= 1) {
        int v = 0;
        if (tid < NPB && tid >= o) v = scn[tid - o];
        __syncthreads();
        if (tid < NPB && tid >= o) scn[tid] += v;
        __syncthreads();
    }
    if (tid < ncnt) {
        int ex = scn[tid] - hist[tid];
        off[node0 + tid] = base + ex;
        cur[tid] = ex;
    }
    __syncthreads();

    // scatter from registers + x-aggregation into LDS
#pragma unroll
    for (int k = 0; k < 8; ++k) {
        if (rec[k] >= 0) {
            int loc = ((unsigned)rec[k]) >> 17;
            int s = rec[k] & 0x1FFFF;
            int p = atomicAdd(&cur[loc], 1);
            esrc[base + p] = s;
            float x0 = x[s * 3 + 0], x1 = x[s * 3 + 1], x2 = x[s * 3 + 2];
            unsafeAtomicAdd(&agg[loc * 3 + 0], x0);
            unsafeAtomicAdd(&agg[loc * 3 + 1], x1);
            unsafeAtomicAdd(&agg[loc * 3 + 2], x2);
        }
    }
    __syncthreads();

    // xin = x_self + agg (in place)
    for (int i = tid; i < ncnt * 3; i += 1024)
        agg[i] += x[node0 * 3 + i];
    __syncthreads();

    // fused layer-1 MLP: 16-node tiles per wave
    int w = tid >> 6, l = tid & 63;
    int m  = l & 15;
    int kg = l >> 4;
    int ntiles = (ncnt + 15) / 16;
    for (int t = w; t < ntiles; t += 16) {
        int nl0 = t * 16;
#pragma unroll 4
        for (int mm = 0; mm < 16; ++mm) {
            int nl = nl0 + mm;
            float tt = 0.0f;
            if (nl < ncnt) {
                float in0 = agg[nl * 3 + 0];
                float in1 = agg[nl * 3 + 1];
                float in2 = agg[nl * 3 + 2];
                tt = fmaxf(sba[l] + in0 * sWa[l] + in1 * sWa[64 + l] + in2 * sWa[128 + l], 0.0f);
            }
            stA[w][mm][l] = f2bf(tt);
        }
        __builtin_amdgcn_wave_barrier();

        short8v A0 = *reinterpret_cast<const short8v*>(&stA[w][m][kg * 8]);
        short8v A1 = *reinterpret_cast<const short8v*>(&stA[w][m][32 + kg * 8]);
#pragma unroll
        for (int cq = 0; cq < 4; ++cq) {
            short8v B0 = *reinterpret_cast<const short8v*>(&sWbT[(16 * cq + m) * 72 + kg * 8]);
            short8v B1 = *reinterpret_cast<const short8v*>(&sWbT[(16 * cq + m) * 72 + 32 + kg * 8]);
            float bb = sbb[16 * cq + m];
            float4v acc = {bb, bb, bb, bb};
            acc = __builtin_amdgcn_mfma_f32_16x16x32_bf16(A0, B0, acc, 0, 0, 0);
            acc = __builtin_amdgcn_mfma_f32_16x16x32_bf16(A1, B1, acc, 0, 0, 0);
#pragma unroll
            for (int i = 0; i < 4; ++i) {
                int nl = nl0 + kg * 4 + i;
                if (nl < ncnt)
                    h1b[(size_t)(node0 + nl) * 64 + 16 * cq + m] = f2bf(fmaxf(acc[i], 0.0f));
            }
        }
        __builtin_amdgcn_wave_barrier();
    }
}

// ---------------- balanced tile partition: smallest t with off[16t]+TCW*t >= target ----------------
__device__ __forceinline__ int tile_bound(const int* __restrict__ off, long long target) {
    int lo = 0, hi = NTILES;
    while (lo < hi) {
        int mid = (lo + hi) >> 1;
        long long v = (long long)off[mid * 16] + (long long)TCW * mid;
        if (v < target) lo = mid + 1; else hi = mid;
    }
    return lo;
}

// ---------------- Layer 2: gather + double MFMA MLP + FUSED graph-sum (no h2) ----------------
__global__ __launch_bounds__(512, 8) void l2_mfma(const unsigned* __restrict__ h1p,   // packed 2xbf16
                                                  const int* __restrict__ off,
                                                  const int* __restrict__ esrc,
                                                  const int* __restrict__ batch,
                                                  const float* __restrict__ W2a,
                                                  const float* __restrict__ b2a,
                                                  const float* __restrict__ W2b,
                                                  const float* __restrict__ b2b,
                                                  float* __restrict__ gsum) {  // [N_GRAPHS][64]
    __shared__ float sba[64], sbb[64];
    __shared__ __align__(16) unsigned short sWaT[64 * 72];   // sWaT[n*72+k] = bf16(W2a[k][n])
    __shared__ __align__(16) unsigned short sWbT[64 * 72];
    __shared__ __align__(16) unsigned short stA[WPB2][16][72];

    int tid = threadIdx.x;
    for (int i = tid; i < 64 * 64; i += BLK2) {
        int k = i >> 6, n = i & 63;
        sWaT[n * 72 + k] = f2bf(W2a[i]);
        sWbT[n * 72 + k] = f2bf(W2b[i]);
    }
    if (tid < 64) { sba[tid] = b2a[tid]; sbb[tid] = b2b[tid]; }
    __syncthreads();

    int w = tid >> 6;
    int l = tid & 63;
    int g = l >> 4;          // edge slot 0..3
    int q = l & 15;          // 8B chunk of 128B row
    int m  = l & 15;
    int kg = l >> 4;
    int wid = blockIdx.x * WPB2 + w;

    const long long TOT = (long long)N_EDGES + (long long)TCW * NTILES;
    int t0 = tile_bound(off, TOT * wid / NWAVES2);
    int t1 = tile_bound(off, TOT * (wid + 1) / NWAVES2);

    for (int t = t0; t < t1; ++t) {
        int nt0 = t * 16;
        // ---- gather 16 nodes -> stA rows (bf16) ----
        for (int mm = 0; mm < 16; ++mm) {
            int n = nt0 + mm;
            int start = off[n], end = off[n + 1];
            int em = max(end - 1, 0);
            float a0 = 0.f, a1 = 0.f, a2 = 0.f, a3 = 0.f;
            if (g == 0) {      // self term once
                uint2 v = *reinterpret_cast<const uint2*>(h1p + (size_t)n * 32 + 2 * q);
                a0 += bl_lo(v.x); a1 += bl_hi(v.x); a2 += bl_lo(v.y); a3 += bl_hi(v.y);
            }
            for (int e = start; e < end; e += 16) {
                int tA = e + g, tB = e + 4 + g, tC = e + 8 + g, tD = e + 12 + g;
                int iA = min(tA, em);
                int iB = min(tB, em);
                int iC = min(tC, em);
                int iD = min(tD, em);
                int sa = esrc[iA], sb = esrc[iB], sc = esrc[iC], sd = esrc[iD];
                uint2 vA = *reinterpret_cast<const uint2*>(h1p + (size_t)sa * 32 + 2 * q);
                uint2 vB = *reinterpret_cast<const uint2*>(h1p + (size_t)sb * 32 + 2 * q);
                uint2 vC = *reinterpret_cast<const uint2*>(h1p + (size_t)sc * 32 + 2 * q);
                uint2 vD = *reinterpret_cast<const uint2*>(h1p + (size_t)sd * 32 + 2 * q);
                unsigned mA = tA < end ? 0xffffffffu : 0u;
                unsigned mB = tB < end ? 0xffffffffu : 0u;
                unsigned mC = tC < end ? 0xffffffffu : 0u;
                unsigned mD = tD < end ? 0xffffffffu : 0u;
                a0 += (bl_lo(vA.x & mA) + bl_lo(vB.x & mB)) + (bl_lo(vC.x & mC) + bl_lo(vD.x & mD));
                a1 += (bl_hi(vA.x & mA) + bl_hi(vB.x & mB)) + (bl_hi(vC.x & mC) + bl_hi(vD.x & mD));
                a2 += (bl_lo(vA.y & mA) + bl_lo(vB.y & mB)) + (bl_lo(vC.y & mC) + bl_lo(vD.y & mD));
                a3 += (bl_hi(vA.y & mA) + bl_hi(vB.y & mB)) + (bl_hi(vC.y & mC) + bl_hi(vD.y & mD));
            }
            a0 += __shfl_xor(a0, 16); a0 += __shfl_xor(a0, 32);
            a1 += __shfl_xor(a1, 16); a1 += __shfl_xor(a1, 32);
            a2 += __shfl_xor(a2, 16); a2 += __shfl_xor(a2, 32);
            a3 += __shfl_xor(a3, 16); a3 += __shfl_xor(a3, 32);
            if (g == 0) {
                uint2 pk;
                pk.x = ((unsigned)f2bf(a1) << 16) | (unsigned)f2bf(a0);
                pk.y = ((unsigned)f2bf(a3) << 16) | (unsigned)f2bf(a2);
                *reinterpret_cast<uint2*>(&stA[w][mm][4 * q]) = pk;
            }
        }
        __builtin_amdgcn_wave_barrier();

        // ---- matmul1: relu(agg @ W2a + b2a), restage as bf16 ----
        short8v A0 = *reinterpret_cast<const short8v*>(&stA[w][m][kg * 8]);
        short8v A1 = *reinterpret_cast<const short8v*>(&stA[w][m][32 + kg * 8]);
#pragma unroll
        for (int cq = 0; cq < 4; ++cq) {
            short8v B0 = *reinterpret_cast<const short8v*>(&sWaT[(16 * cq + m) * 72 + kg * 8]);
            short8v B1 = *reinterpret_cast<const short8v*>(&sWaT[(16 * cq + m) * 72 + 32 + kg * 8]);
            float bb = sba[16 * cq + m];
            float4v acc = {bb, bb, bb, bb};
            acc = __builtin_amdgcn_mfma_f32_16x16x32_bf16(A0, B0, acc, 0, 0, 0);
            acc = __builtin_amdgcn_mfma_f32_16x16x32_bf16(A1, B1, acc, 0, 0, 0);
#pragma unroll
            for (int i = 0; i < 4; ++i)
                stA[w][kg * 4 + i][16 * cq + m] = f2bf(fmaxf(acc[i], 0.0f));
        }
        __builtin_amdgcn_wave_barrier();

        // ---- matmul2 + fused per-graph sum (pool) ----
        int gLo = batch[nt0];
        int gHi = batch[nt0 + 15];
        bool uni = (gLo == gHi);
        short8v C0 = *reinterpret_cast<const short8v*>(&stA[w][m][kg * 8]);
        short8v C1 = *reinterpret_cast<const short8v*>(&stA[w][m][32 + kg * 8]);
#pragma unroll
        for (int cq = 0; cq < 4; ++cq) {
            short8v B0 = *reinterpret_cast<const short8v*>(&sWbT[(16 * cq + m) * 72 + kg * 8]);
            short8v B1 = *reinterpret_cast<const short8v*>(&sWbT[(16 * cq + m) * 72 + 32 + kg * 8]);
            float bb = sbb[16 * cq + m];
            float4v acc = {bb, bb, bb, bb};
            acc = __builtin_amdgcn_mfma_f32_16x16x32_bf16(C0, B0, acc, 0, 0, 0);
            acc = __builtin_amdgcn_mfma_f32_16x16x32_bf16(C1, B1, acc, 0, 0, 0);
            if (uni) {
                float s = fmaxf(acc[0], 0.0f) + fmaxf(acc[1], 0.0f)
                        + fmaxf(acc[2], 0.0f) + fmaxf(acc[3], 0.0f);
                s += __shfl_xor(s, 16);
                s += __shfl_xor(s, 32);
                if (kg == 0) atomicAdd(&gsum[gLo * 64 + 16 * cq + m], s);
            } else {
#pragma unroll
                for (int i = 0; i < 4; ++i) {
                    int gi = batch[nt0 + kg * 4 + i];
                    atomicAdd(&gsum[gi * 64 + 16 * cq + m], fmaxf(acc[i], 0.0f));
                }
            }
        }
        __builtin_amdgcn_wave_barrier();
    }
}

// ---------------- Final: divide graph sums by counts ----------------
__global__ __launch_bounds__(64) void poolDiv(const float* __restrict__ gsum,
                                              const int* __restrict__ batch,
                                              float* __restrict__ out) {
    int g = blockIdx.x;
    int j = threadIdx.x;

    int lo = 0, hi = N_NODES;
    while (lo < hi) { int mid = (lo + hi) >> 1; if (batch[mid] < g) lo = mid + 1; else hi = mid; }
    int start = lo;
    lo = start; hi = N_NODES;
    while (lo < hi) { int mid = (lo + hi) >> 1; if (batch[mid] < g + 1) lo = mid + 1; else hi = mid; }
    int end = lo;

    float cnt = (float)((end - start) > 1 ? (end - start) : 1);
    out[g * 64 + j] = gsum[g * 64 + j] / cnt;
}

extern "C" void kernel_launch(void* const* d_in, const int* in_sizes, int n_in,
                              void* d_out, int out_size, void* d_ws, size_t ws_size,
                              hipStream_t stream) {
    const float* x    = (const float*)d_in[0];
    const int*   ei   = (const int*)d_in[1];
    const int*   bat  = (const int*)d_in[2];
    const float* W1a  = (const float*)d_in[3];
    const float* b1a  = (const float*)d_in[4];
    const float* W1b  = (const float*)d_in[5];
    const float* b1b  = (const float*)d_in[6];
    const float* W2a  = (const float*)d_in[7];
    const float* b2a  = (const float*)d_in[8];
    const float* W2b  = (const float*)d_in[9];
    const float* b2b  = (const float*)d_in[10];
    float* out = (float*)d_out;

    const int* src = ei;
    const int* dst = ei + N_EDGES;

    char* ws = (char*)d_ws;
    auto alignup = [](size_t v) { return (v + 255) & ~(size_t)255; };
    int*   bcnt  = (int*)ws;                       ws += alignup((size_t)NBUCK * 16 * 4);
    int*   off   = (int*)ws;                       ws += alignup((size_t)(N_NODES + 1) * 4);
    int*   esrc  = (int*)ws;                       ws += alignup((size_t)N_EDGES * 4);
    unsigned short* h1b = (unsigned short*)ws;     ws += alignup((size_t)N_NODES * HID * 2);
    float* gsum  = (float*)ws;                     ws += alignup((size_t)N_GRAPHS * 64 * 4);
    int*   bbuf  = (int*)ws;

    hipMemsetAsync(bcnt, 0, (size_t)NBUCK * 16 * 4, stream);
    hipMemsetAsync(gsum, 0, (size_t)N_GRAPHS * 64 * 4, stream);

    bucketA<<<NBLKA, BLKA, 0, stream>>>(src, dst, bcnt, bbuf);
    bucketB<<<NBUCK, 1024, 0, stream>>>(bbuf, bcnt, x, W1a, b1a, W1b, b1b, off, esrc, h1b);
    l2_mfma<<<NBLK2, BLK2, 0, stream>>>((const unsigned*)h1b, off, esrc, bat, W2a, b2a, W2b, b2b, gsum);
    poolDiv<<<N_GRAPHS, 64, 0, stream>>>(gsum, bat, out);
}